// Round 16
// baseline (271.361 us; speedup 1.0000x reference)
//
#include <hip/hip_runtime.h>
#include <hip/hip_bf16.h>
#include <math.h>

typedef _Float16 f16;
typedef __attribute__((ext_vector_type(8))) _Float16 f16x8;
typedef __attribute__((ext_vector_type(4))) _Float16 f16x4;
typedef __attribute__((ext_vector_type(4))) float f32x4;

#define S_LEN 4096
#define NHEAD 8
#define HDIM 64
#define EMB 512
#define KDIM 512
#define LOG2E 1.4426950408889634f

#if __has_builtin(__builtin_amdgcn_exp2f)
#define EXP2F(x) __builtin_amdgcn_exp2f(x)
#else
#define EXP2F(x) exp2f(x)
#endif

// direct HBM->LDS 16B copy: lds dest = wave-uniform base (+ lane*16 by HW),
// global src is per-lane. CK-style addrspace casts (flat->AS3 = low-32 trunc).
__device__ __forceinline__ void g2l16(const void* g, void* l) {
  __builtin_amdgcn_global_load_lds(
      reinterpret_cast<const __attribute__((address_space(1))) unsigned int*>(
          reinterpret_cast<uintptr_t>(g)),
      reinterpret_cast<__attribute__((address_space(3))) unsigned int*>(
          static_cast<unsigned int>(reinterpret_cast<uintptr_t>(l))),
      16, 0, 0);
}

// ---------------- fused prep: x cast + w_qkv transpose + w_o transpose ----------------
__global__ __launch_bounds__(256) void prep_kernel(
    const float* __restrict__ x, f16* __restrict__ xb,
    const float* __restrict__ w_qkv, f16* __restrict__ wqkvt,
    const float* __restrict__ w_o, f16* __restrict__ wot) {
  __shared__ f16 tile[64][65];  // +1 pad: column reads conflict-free
  const int bid = blockIdx.x;
  const int tid = threadIdx.x;
  if (bid < 4096) {
    const int i = (bid * 256 + tid) * 4;
    float4 v = *(const float4*)(x + i);
    f16x4 o = { (f16)v.x, (f16)v.y, (f16)v.z, (f16)v.w };
    *(f16x4*)(xb + i) = o;
    return;
  }
  const float* in;
  f16* out;
  int R, C, c0, r0;
  if (bid < 4288) {
    const int t = bid - 4096;
    in = w_qkv; out = wqkvt; R = 512; C = 1536;
    c0 = (t % 24) * 64; r0 = (t / 24) * 64;
  } else {
    const int t = bid - 4288;
    in = w_o; out = wot; R = 512; C = 512;
    c0 = (t & 7) * 64; r0 = (t >> 3) * 64;
  }
#pragma unroll
  for (int i = 0; i < 16; ++i) {
    const int idx = i * 256 + tid;
    const int lr = idx >> 6, lc = idx & 63;
    tile[lr][lc] = (f16)in[(size_t)(r0 + lr) * C + (c0 + lc)];  // coalesced read
  }
  __syncthreads();
#pragma unroll
  for (int i = 0; i < 16; ++i) {
    const int idx = i * 256 + tid;
    const int lc = idx >> 6, lr = idx & 63;
    out[(size_t)(c0 + lc) * R + (r0 + lr)] = tile[lr][lc];      // coalesced write
  }
}

// ---------------- GEMM: C[M][N] = A[M][K] * Bt[N][K]^T + bias ----------------
// BK=32, linear LDS, gload_lds staging, 2-barrier loop (m97 form).
// MODE 0: epilogue bounces C through LDS -> coalesced f16x8 scatter to Q/K/V.
// MODE 1: direct f32 C+bias stores.
#define TM 128
#define TK 32

template<int MODE, int TN>
__global__ __launch_bounds__(256) void gemm_bt_kernel(
    const f16* __restrict__ A, const f16* __restrict__ Bt, const float* __restrict__ bias,
    f16* __restrict__ Qo, f16* __restrict__ Ko, f16* __restrict__ Vo,
    float* __restrict__ Co, int M, int N) {
  constexpr int JN = TN / 32;    // B-frags / acc cols per wave
  constexpr int BCH = TN / 64;   // B staging chunks per wave
  constexpr int SMEMSZ = (MODE == 0) ? (128 * 136 * 2) : (8192 + TN * TK * 2);
  __shared__ __align__(16) char smem[SMEMSZ];
  f16 (*As)[TK] = (f16 (*)[TK])smem;             // [TM][TK], 8 KB
  f16 (*Bs)[TK] = (f16 (*)[TK])(smem + 8192);    // [TN][TK]
  const int m0 = blockIdx.x * TM, n0 = blockIdx.y * TN;
  const int tid = threadIdx.x;
  const int lane = tid & 63, wid = tid >> 6;
  const int wr = wid >> 1, wc = wid & 1;
  const int g = lane >> 4, q16 = lane & 15;

  // staging geometry: chunk = 16 rows = 1024 B; lane l -> row l>>2, 16B slot l&3.
  const int srow = lane >> 2;
  const int skof = (lane & 3) * 8;
  const f16* Ag[2]; char* Al[2];
#pragma unroll
  for (int cb = 0; cb < 2; ++cb) {
    const int ch = wid * 2 + cb;
    Ag[cb] = A + (size_t)(m0 + ch * 16 + srow) * KDIM + skof;
    Al[cb] = (char*)As + ch * 1024;
  }
  const f16* Bg[BCH]; char* Bl[BCH];
#pragma unroll
  for (int cb = 0; cb < BCH; ++cb) {
    const int ch = wid * BCH + cb;
    Bg[cb] = Bt + (size_t)(n0 + ch * 16 + srow) * KDIM + skof;
    Bl[cb] = (char*)Bs + ch * 1024;
  }

  f32x4 zero = {0.f, 0.f, 0.f, 0.f};
  f32x4 acc[4][JN];
#pragma unroll
  for (int i = 0; i < 4; i++)
#pragma unroll
    for (int j = 0; j < JN; j++) acc[i][j] = zero;

  for (int kk = 0; kk < KDIM; kk += TK) {
    g2l16(Ag[0] + kk, Al[0]);
    g2l16(Ag[1] + kk, Al[1]);
#pragma unroll
    for (int cb = 0; cb < BCH; ++cb) g2l16(Bg[cb] + kk, Bl[cb]);
    __syncthreads();   // drains vmcnt (gload_lds) + joins waves
    f16x8 af[4], bfr[JN];
#pragma unroll
    for (int i = 0; i < 4; i++) af[i] = *(const f16x8*)&As[wr * 64 + i * 16 + q16][8 * g];
#pragma unroll
    for (int j = 0; j < JN; j++) bfr[j] = *(const f16x8*)&Bs[wc * (TN / 2) + j * 16 + q16][8 * g];
#pragma unroll
    for (int i = 0; i < 4; i++)
#pragma unroll
      for (int j = 0; j < JN; j++)
        acc[i][j] = __builtin_amdgcn_mfma_f32_16x16x32_f16(af[i], bfr[j], acc[i][j], 0, 0, 0);
    __syncthreads();   // all ds_reads done before next-iter staging overwrites
  }

  if (MODE == 1) {
#pragma unroll
    for (int i = 0; i < 4; i++)
#pragma unroll
      for (int j = 0; j < JN; j++) {
        const int n = n0 + wc * (TN / 2) + j * 16 + q16;
        const float bs = bias[n];
        const int mbase = m0 + wr * 64 + i * 16 + 4 * g;
#pragma unroll
        for (int r = 0; r < 4; r++) Co[(size_t)(mbase + r) * N + n] = acc[i][j][r] + bs;
      }
  } else {
    // ---- LDS-bounce epilogue: acc(+bias,+Q-scale) -> Cs f16 -> coalesced 16B scatter ----
    f16 (*Cs)[136] = (f16 (*)[136])smem;   // aliases As/Bs (dead after final barrier)
#pragma unroll
    for (int i = 0; i < 4; i++)
#pragma unroll
      for (int j = 0; j < JN; j++) {
        const int n = n0 + wc * (TN / 2) + j * 16 + q16;
        const float bs = bias[n];
        const int rr_n = n % 192;                         // section uniform per (i,j)
        const float scale = (rr_n < 64) ? 0.125f : 1.0f;  // Q pre-scaled by 1/8
        const int mrow = wr * 64 + i * 16 + 4 * g;
        const int ncol = wc * (TN / 2) + j * 16 + q16;
#pragma unroll
        for (int r = 0; r < 4; r++)
          Cs[mrow + r][ncol] = (f16)((acc[i][j][r] + bs) * scale);
      }
    __syncthreads();
    const int cc = tid & 15;
    const int nn = n0 + 8 * cc;
    const int hh = nn / 192;
    const int rr = nn - 192 * hh;
    f16* base = (rr < 64) ? Qo : (rr < 128) ? Ko : Vo;
    const int d0 = rr & 63;
#pragma unroll
    for (int it = 0; it < 8; ++it) {
      const int m = (tid >> 4) + 16 * it;
      f16x8 v = *(const f16x8*)&Cs[m][8 * cc];
      const int mglob = m0 + m;
      const int b = mglob >> 12, s = mglob & (S_LEN - 1);
      const size_t bh = (size_t)b * NHEAD + hh;
      *(f16x8*)(base + (bh * S_LEN + s) * HDIM + d0) = v;
    }
  }
}

// ---------------- sliding-window flash attention (LDS window, split-K, 16 waves) ----------------
#define VSOFF 49152

__global__ __launch_bounds__(1024) void attn_kernel(
    const f16* __restrict__ Q, const f16* __restrict__ K,
    const f16* __restrict__ V, f16* __restrict__ O) {
  __shared__ __align__(16) char smem[98304];

  const int wg = blockIdx.x;
  const int vv = (wg & 7) * 64 + (wg >> 3);    // XCD swizzle (512 % 8 == 0, bijective)
  const int bh = vv >> 5, qc = vv & 31;        // 32 query-chunks of 128 per bh
  const int b = bh >> 3, h = bh & 7;
  const int tid = threadIdx.x;
  const int wid = tid >> 6, lane = tid & 63;
  const int qwv = wid & 7;                     // query-wave id (0..7)
  const int kh = wid >> 3;                     // key half: 0 -> tiles 0-4, 1 -> tiles 5-8
  const int g = lane >> 4, q16 = lane & 15;
  const int qb = qc * 128;
  const int wb = qb - 128;
  const int qw = qb + qwv * 16;                // this wave's 16 queries
  const int qg = qw + q16;

  const f16* Kb_g = K + (size_t)bh * S_LEN * HDIM;
  const f16* Vb_g = V + (size_t)bh * S_LEN * HDIM;

#pragma unroll
  for (int rd = 0; rd < 3; ++rd) {
    const int idx = rd * 1024 + tid;
    const int r = idx >> 3, sl = idx & 7;
    const int key = min(max(wb + r, 0), S_LEN - 1); // clamped rows masked in compute
    int4 kvv = *(const int4*)(Kb_g + (size_t)key * HDIM + sl * 8);
    *(int4*)(smem + r * 128 + ((sl ^ (r & 7)) << 4)) = kvv;
  }
#pragma unroll
  for (int rd = 0; rd < 3; ++rd) {
    const int idx = rd * 1024 + tid;
    const int r = idx >> 3, c8 = (idx & 7) * 8;
    const int key = min(max(wb + r, 0), S_LEN - 1);
    int4 vvv = *(const int4*)(Vb_g + (size_t)key * HDIM + c8);
    *(int4*)(smem + VSOFF + (c8 >> 4) * 12288 + (r >> 2) * 128 + (r & 3) * 32 + ((c8 & 8) << 1)) = vvv;
  }
  __syncthreads();

  const f16* Qb = Q + ((size_t)bh * S_LEN + qw) * HDIM;
  f16x8 qf0 = *(const f16x8*)(Qb + q16 * HDIM + 8 * g);
  f16x8 qf1 = *(const f16x8*)(Qb + q16 * HDIM + 32 + 8 * g);

  f32x4 zero = {0.f, 0.f, 0.f, 0.f};
  f32x4 o[4];
#pragma unroll
  for (int dt = 0; dt < 4; dt++) o[dt] = zero;
  float m_run = 0.f;   // static base; vote-guarded rescale
  float l_run = 0.f;

  const unsigned troff = (unsigned)(g * 128 + q16 * 8);

  auto do_tile = [&](int t) {
    const int kAp = qwv * 16 + 32 * t;
    const int kBp = kAp + 16;            // may be 384 (qwv=7,t=8): in-smem garbage, fully masked
    const int rrA = kAp + q16;
    const int rrB = kBp + q16;
    f16x8 ka0 = *(const f16x8*)(smem + rrA * 128 + (((g    ) ^ (rrA & 7)) << 4));
    f16x8 ka1 = *(const f16x8*)(smem + rrA * 128 + (((g + 4) ^ (rrA & 7)) << 4));
    f16x8 kb0 = *(const f16x8*)(smem + rrB * 128 + (((g    ) ^ (rrB & 7)) << 4));
    f16x8 kb1 = *(const f16x8*)(smem + rrB * 128 + (((g + 4) ^ (rrB & 7)) << 4));

    f32x4 sA = zero, sB = zero;
    __builtin_amdgcn_s_setprio(1);
    sA = __builtin_amdgcn_mfma_f32_16x16x32_f16(ka0, qf0, sA, 0, 0, 0);
    sA = __builtin_amdgcn_mfma_f32_16x16x32_f16(ka1, qf1, sA, 0, 0, 0);
    sB = __builtin_amdgcn_mfma_f32_16x16x32_f16(kb0, qf0, sB, 0, 0, 0);
    sB = __builtin_amdgcn_mfma_f32_16x16x32_f16(kb1, qf1, sB, 0, 0, 0);
    __builtin_amdgcn_s_setprio(0);

    float sv[8];
    float mx = -INFINITY;
#pragma unroll
    for (int i = 0; i < 4; i++) {
      const int kgA = wb + kAp + 4 * g + i;
      const int kgB = wb + kBp + 4 * g + i;
      const bool okA = ((unsigned)(kgA - qg + 128) <= 256u) && ((unsigned)kgA < S_LEN);
      const bool okB = ((unsigned)(kgB - qg + 128) <= 256u) && ((unsigned)kgB < S_LEN);
      sv[i]     = okA ? sA[i] : -INFINITY;
      sv[i + 4] = okB ? sB[i] : -INFINITY;
      mx = fmaxf(mx, fmaxf(sv[i], sv[i + 4]));
    }

    float pA[4], pB[4];
#pragma unroll
    for (int i = 0; i < 4; i++) {
      pA[i] = EXP2F((sv[i] - m_run) * LOG2E);
      pB[i] = EXP2F((sv[i + 4] - m_run) * LOG2E);
    }

    if (__builtin_expect(!__all(mx - m_run <= 8.f), 0)) {
      float mxq = fmaxf(mx, __shfl_xor(mx, 16));
      mxq = fmaxf(mxq, __shfl_xor(mxq, 32));
      const float mnew = fmaxf(m_run, mxq);
      const float resc = EXP2F((m_run - mnew) * LOG2E);
#pragma unroll
      for (int i = 0; i < 4; i++) { pA[i] *= resc; pB[i] *= resc; }
      l_run *= resc;
      float ri[4];
#pragma unroll
      for (int i = 0; i < 4; i++) ri[i] = __shfl(resc, 4 * g + i);
#pragma unroll
      for (int dt = 0; dt < 4; dt++)
#pragma unroll
        for (int i = 0; i < 4; i++) o[dt][i] *= ri[i];
      m_run = mnew;
    }

    f16x4 pfA, pfB;
#pragma unroll
    for (int i = 0; i < 4; i++) {
      l_run += pA[i] + pB[i];
      pfA[i] = (f16)pA[i];
      pfB[i] = (f16)pB[i];
    }

    const int kcA = kAp;
    const int kcB = min(kBp, 368);   // block index <= 95; clamped tiles fully masked
    f16x4 bA[4], bB[4];
#pragma unroll
    for (int dt = 0; dt < 4; ++dt) {
      unsigned aA = (unsigned)(uintptr_t)(smem + VSOFF + dt * 12288 + (kcA >> 2) * 128) + troff;
      unsigned aB = (unsigned)(uintptr_t)(smem + VSOFF + dt * 12288 + (kcB >> 2) * 128) + troff;
      asm volatile("ds_read_b64_tr_b16 %0, %1" : "=v"(bA[dt]) : "v"(aA));
      asm volatile("ds_read_b64_tr_b16 %0, %1" : "=v"(bB[dt]) : "v"(aB));
    }
    asm volatile("s_waitcnt lgkmcnt(0)" ::: "memory");
    __builtin_amdgcn_sched_barrier(0);

    __builtin_amdgcn_s_setprio(1);
#pragma unroll
    for (int dt = 0; dt < 4; dt++) {
      o[dt] = __builtin_amdgcn_mfma_f32_16x16x16f16(pfA, bA[dt], o[dt], 0, 0, 0);
      o[dt] = __builtin_amdgcn_mfma_f32_16x16x16f16(pfB, bB[dt], o[dt], 0, 0, 0);
    }
    __builtin_amdgcn_s_setprio(0);
  };

  if (kh == 0) {
#pragma unroll
    for (int t = 0; t < 5; ++t) do_tile(t);
  } else {
#pragma unroll
    for (int t = 5; t < 9; ++t) do_tile(t);
  }

  l_run += __shfl_xor(l_run, 16);
  l_run += __shfl_xor(l_run, 32);

  // ---- split-K merge ----
  float* oS = (float*)smem;                    // [8][64][16] f32 = 32 KB
  float* lS = (float*)(smem + 32768);          // [8][64]
  float* mS = (float*)(smem + 34816);          // [8][64]
  __syncthreads();   // all waves done reading K/V LDS
  if (kh == 1) {
#pragma unroll
    for (int dt = 0; dt < 4; dt++)
#pragma unroll
      for (int i = 0; i < 4; i++)
        oS[(qwv * 64 + lane) * 16 + dt * 4 + i] = o[dt][i];
    lS[qwv * 64 + lane] = l_run;
    mS[qwv * 64 + lane] = m_run;
  }
  __syncthreads();   // publish visible
  if (kh == 0) {
    const float mB = mS[qwv * 64 + lane];
    const float lB = lS[qwv * 64 + lane];
    const float m = fmaxf(m_run, mB);
    const float fA = EXP2F((m_run - m) * LOG2E);
    const float fB = EXP2F((mB - m) * LOG2E);
    const float linv = 1.f / (l_run * fA + lB * fB);
    const float aA = fA * linv, aB = fB * linv;   // per query q16
    float aAi[4], aBi[4];
#pragma unroll
    for (int i = 0; i < 4; i++) {
      aAi[i] = __shfl(aA, 4 * g + i);             // per query 4g+i
      aBi[i] = __shfl(aB, 4 * g + i);
    }
    float* st = (float*)(smem + VSOFF) + qwv * 1024;   // 8 x 4 KB
#pragma unroll
    for (int dt = 0; dt < 4; dt++)
#pragma unroll
      for (int i = 0; i < 4; i++) {
        const float ov = o[dt][i] * aAi[i] + oS[(qwv * 64 + lane) * 16 + dt * 4 + i] * aBi[i];
        st[(4 * g + i) * 64 + dt * 16 + q16] = ov;
      }
    const int r = lane >> 2, c0 = (lane & 3) * 16;
    const float* sp = st + r * 64 + c0;
    f16x8 h0, h1;
#pragma unroll
    for (int j = 0; j < 8; j++) { h0[j] = (f16)sp[j]; h1[j] = (f16)sp[8 + j]; }
    f16* dst = O + ((size_t)b * S_LEN + qw + r) * EMB + h * HDIM + c0;
    *(f16x8*)dst = h0;
    *(f16x8*)(dst + 8) = h1;
  }
}

// ---------------- launch ----------------
// PROBE ROUND 2: attn x8 AND out-proj x8 (both idempotent, deterministic).
// t_attn + t_out = (dur_us - 65.4) / 7;  gaps+prep = 65.4 - 20.3 - (t_attn+t_out).
extern "C" void kernel_launch(void* const* d_in, const int* in_sizes, int n_in,
                              void* d_out, int out_size, void* d_ws, size_t ws_size,
                              hipStream_t stream) {
  const float* x     = (const float*)d_in[0];
  const float* w_qkv = (const float*)d_in[1];
  const float* b_qkv = (const float*)d_in[2];
  const float* w_o   = (const float*)d_in[3];
  const float* b_o   = (const float*)d_in[4];
  float* out = (float*)d_out;

  char* ws = (char*)d_ws;
  f16* xb    = (f16*)(ws);                 // [8192][512]        8.0 MiB
  f16* wqkvt = (f16*)(ws + 8388608);       // [1536][512]        1.5 MiB
  f16* wot   = (f16*)(ws + 9961472);       // [512][512]         0.5 MiB
  f16* Qs    = (f16*)(ws + 10485760);      // [16][4096][64]     8 MiB
  f16* Ks    = (f16*)(ws + 18874368);      // [16][4096][64]     8 MiB
  f16* Vs    = (f16*)(ws + 27262976);      // [16][4096][64]     8 MiB (row-major)
  f16* attn  = (f16*)(ws + 35651584);      // [8192][512]        8 MiB

  prep_kernel<<<4352, 256, 0, stream>>>(x, xb, w_qkv, wqkvt, w_o, wot);
  gemm_bt_kernel<0, 128><<<dim3(64, 12), 256, 0, stream>>>(xb, wqkvt, b_qkv, Qs, Ks, Vs,
                                                           (float*)nullptr, 8192, 1536);
  for (int rep = 0; rep < 8; ++rep)
    attn_kernel<<<512, 1024, 0, stream>>>(Qs, Ks, Vs, attn);
  for (int rep = 0; rep < 8; ++rep)
    gemm_bt_kernel<1, 64><<<dim3(64, 8), 256, 0, stream>>>(attn, wot, b_o,
                                                           (f16*)nullptr, (f16*)nullptr, (f16*)nullptr,
                                                           out, 8192, 512);
}

// Round 17
// 66.270 us; speedup vs baseline: 4.0947x; 4.0947x over previous
//
#include <hip/hip_runtime.h>
#include <hip/hip_bf16.h>
#include <math.h>

typedef _Float16 f16;
typedef __attribute__((ext_vector_type(8))) _Float16 f16x8;
typedef __attribute__((ext_vector_type(4))) _Float16 f16x4;
typedef __attribute__((ext_vector_type(4))) float f32x4;

#define S_LEN 4096
#define NHEAD 8
#define HDIM 64
#define EMB 512
#define KDIM 512
#define LOG2E 1.4426950408889634f

#if __has_builtin(__builtin_amdgcn_exp2f)
#define EXP2F(x) __builtin_amdgcn_exp2f(x)
#else
#define EXP2F(x) exp2f(x)
#endif

// direct HBM->LDS 16B copy: lds dest = wave-uniform base (+ lane*16 by HW),
// global src is per-lane. CK-style addrspace casts (flat->AS3 = low-32 trunc).
__device__ __forceinline__ void g2l16(const void* g, void* l) {
  __builtin_amdgcn_global_load_lds(
      reinterpret_cast<const __attribute__((address_space(1))) unsigned int*>(
          reinterpret_cast<uintptr_t>(g)),
      reinterpret_cast<__attribute__((address_space(3))) unsigned int*>(
          static_cast<unsigned int>(reinterpret_cast<uintptr_t>(l))),
      16, 0, 0);
}

// ---------------- prep: weight transposes only (x-cast fused into QKV GEMM) ----------------
// blocks [0,192): transpose w_qkv 512x1536 -> [1536][512] f16  (24x8 tiles)
// blocks [192,256): transpose w_o 512x512  -> [512][512]  f16  (8x8 tiles)
__global__ __launch_bounds__(256) void prep_kernel(
    const float* __restrict__ w_qkv, f16* __restrict__ wqkvt,
    const float* __restrict__ w_o, f16* __restrict__ wot) {
  __shared__ f16 tile[64][65];  // +1 pad: column reads conflict-free
  const int bid = blockIdx.x;
  const int tid = threadIdx.x;
  const float* in;
  f16* out;
  int R, C, c0, r0;
  if (bid < 192) {
    in = w_qkv; out = wqkvt; R = 512; C = 1536;
    c0 = (bid % 24) * 64; r0 = (bid / 24) * 64;
  } else {
    const int t = bid - 192;
    in = w_o; out = wot; R = 512; C = 512;
    c0 = (t & 7) * 64; r0 = (t >> 3) * 64;
  }
#pragma unroll
  for (int i = 0; i < 16; ++i) {
    const int idx = i * 256 + tid;
    const int lr = idx >> 6, lc = idx & 63;
    tile[lr][lc] = (f16)in[(size_t)(r0 + lr) * C + (c0 + lc)];  // coalesced read
  }
  __syncthreads();
#pragma unroll
  for (int i = 0; i < 16; ++i) {
    const int idx = i * 256 + tid;
    const int lc = idx >> 6, lr = idx & 63;
    out[(size_t)(c0 + lc) * R + (r0 + lr)] = tile[lr][lc];      // coalesced write
  }
}

// ---------------- GEMM: C[M][N] = A[M][K] * Bt[N][K]^T + bias ----------------
// BK=32, linear LDS, 2-barrier loop (m97 form).
// MODE 0: A is f32 (raw x) -> reg-staged with fused f32->f16 cast (kills the
//         standalone cast kernel); B via gload_lds. Epilogue: LDS-bounce scatter.
// MODE 1: A is f16 -> gload_lds both; direct f32 C+bias stores.
#define TM 128
#define TK 32

template<int MODE, int TN>
__global__ __launch_bounds__(256) void gemm_bt_kernel(
    const void* __restrict__ Aptr, const f16* __restrict__ Bt, const float* __restrict__ bias,
    f16* __restrict__ Qo, f16* __restrict__ Ko, f16* __restrict__ Vo,
    float* __restrict__ Co, int M, int N) {
  constexpr int JN = TN / 32;    // B-frags / acc cols per wave
  constexpr int BCH = TN / 64;   // B staging chunks per wave
  constexpr int SMEMSZ = (MODE == 0) ? (128 * 136 * 2) : (8192 + TN * TK * 2);
  __shared__ __align__(16) char smem[SMEMSZ];
  f16 (*As)[TK] = (f16 (*)[TK])smem;             // [TM][TK], 8 KB
  f16 (*Bs)[TK] = (f16 (*)[TK])(smem + 8192);    // [TN][TK]
  const int m0 = blockIdx.x * TM, n0 = blockIdx.y * TN;
  const int tid = threadIdx.x;
  const int lane = tid & 63, wid = tid >> 6;
  const int wr = wid >> 1, wc = wid & 1;
  const int g = lane >> 4, q16 = lane & 15;

  // staging geometry: chunk = 16 rows; lane l -> row l>>2, 8-elem slot l&3.
  // MODE 0: 8 f32 -> cvt -> ds_write_b128 at byte chunk_base + l*16
  //         ((l>>2)*64 + (l&3)*16 == 16*l, same linear layout as gload_lds).
  const int srow = lane >> 2;
  const int skof = (lane & 3) * 8;
  const float* A32[2] = {nullptr, nullptr};
  const f16* Ag[2] = {nullptr, nullptr};
  char* Al[2];
#pragma unroll
  for (int cb = 0; cb < 2; ++cb) {
    const int ch = wid * 2 + cb;
    Al[cb] = (char*)As + ch * 1024;
    if (MODE == 0)
      A32[cb] = (const float*)Aptr + (size_t)(m0 + ch * 16 + srow) * KDIM + skof;
    else
      Ag[cb] = (const f16*)Aptr + (size_t)(m0 + ch * 16 + srow) * KDIM + skof;
  }
  const f16* Bg[BCH]; char* Bl[BCH];
#pragma unroll
  for (int cb = 0; cb < BCH; ++cb) {
    const int ch = wid * BCH + cb;
    Bg[cb] = Bt + (size_t)(n0 + ch * 16 + srow) * KDIM + skof;
    Bl[cb] = (char*)Bs + ch * 1024;
  }

  f32x4 zero = {0.f, 0.f, 0.f, 0.f};
  f32x4 acc[4][JN];
#pragma unroll
  for (int i = 0; i < 4; i++)
#pragma unroll
    for (int j = 0; j < JN; j++) acc[i][j] = zero;

  for (int kk = 0; kk < KDIM; kk += TK) {
#pragma unroll
    for (int cb = 0; cb < BCH; ++cb) g2l16(Bg[cb] + kk, Bl[cb]);
    if (MODE == 0) {
#pragma unroll
      for (int cb = 0; cb < 2; ++cb) {
        float4 v0 = *(const float4*)(A32[cb] + kk);
        float4 v1 = *(const float4*)(A32[cb] + kk + 4);
        f16x8 pk = { (f16)v0.x, (f16)v0.y, (f16)v0.z, (f16)v0.w,
                     (f16)v1.x, (f16)v1.y, (f16)v1.z, (f16)v1.w };
        *(f16x8*)(Al[cb] + lane * 16) = pk;
      }
    } else {
      g2l16(Ag[0] + kk, Al[0]);
      g2l16(Ag[1] + kk, Al[1]);
    }
    __syncthreads();   // drains vmcnt (gload_lds) + lgkm (ds_write) + joins waves
    f16x8 af[4], bfr[JN];
#pragma unroll
    for (int i = 0; i < 4; i++) af[i] = *(const f16x8*)&As[wr * 64 + i * 16 + q16][8 * g];
#pragma unroll
    for (int j = 0; j < JN; j++) bfr[j] = *(const f16x8*)&Bs[wc * (TN / 2) + j * 16 + q16][8 * g];
#pragma unroll
    for (int i = 0; i < 4; i++)
#pragma unroll
      for (int j = 0; j < JN; j++)
        acc[i][j] = __builtin_amdgcn_mfma_f32_16x16x32_f16(af[i], bfr[j], acc[i][j], 0, 0, 0);
    __syncthreads();   // all ds_reads done before next-iter staging overwrites
  }

  if (MODE == 1) {
#pragma unroll
    for (int i = 0; i < 4; i++)
#pragma unroll
      for (int j = 0; j < JN; j++) {
        const int n = n0 + wc * (TN / 2) + j * 16 + q16;
        const float bs = bias[n];
        const int mbase = m0 + wr * 64 + i * 16 + 4 * g;
#pragma unroll
        for (int r = 0; r < 4; r++) Co[(size_t)(mbase + r) * N + n] = acc[i][j][r] + bs;
      }
  } else {
    // ---- LDS-bounce epilogue: acc(+bias,+Q-scale) -> Cs f16 -> coalesced 16B scatter ----
    f16 (*Cs)[136] = (f16 (*)[136])smem;   // aliases As/Bs (dead after final barrier)
#pragma unroll
    for (int i = 0; i < 4; i++)
#pragma unroll
      for (int j = 0; j < JN; j++) {
        const int n = n0 + wc * (TN / 2) + j * 16 + q16;
        const float bs = bias[n];
        const int rr_n = n % 192;                         // section uniform per (i,j)
        const float scale = (rr_n < 64) ? 0.125f : 1.0f;  // Q pre-scaled by 1/8
        const int mrow = wr * 64 + i * 16 + 4 * g;
        const int ncol = wc * (TN / 2) + j * 16 + q16;
#pragma unroll
        for (int r = 0; r < 4; r++)
          Cs[mrow + r][ncol] = (f16)((acc[i][j][r] + bs) * scale);
      }
    __syncthreads();
    const int cc = tid & 15;
    const int nn = n0 + 8 * cc;
    const int hh = nn / 192;
    const int rr = nn - 192 * hh;
    f16* base = (rr < 64) ? Qo : (rr < 128) ? Ko : Vo;
    const int d0 = rr & 63;
#pragma unroll
    for (int it = 0; it < 8; ++it) {
      const int m = (tid >> 4) + 16 * it;
      f16x8 v = *(const f16x8*)&Cs[m][8 * cc];
      const int mglob = m0 + m;
      const int b = mglob >> 12, s = mglob & (S_LEN - 1);
      const size_t bh = (size_t)b * NHEAD + hh;
      *(f16x8*)(base + (bh * S_LEN + s) * HDIM + d0) = v;
    }
  }
}

// ---------------- sliding-window flash attention (LDS window, split-K, 16 waves) ----------------
#define VSOFF 49152

__global__ __launch_bounds__(1024) void attn_kernel(
    const f16* __restrict__ Q, const f16* __restrict__ K,
    const f16* __restrict__ V, f16* __restrict__ O) {
  __shared__ __align__(16) char smem[98304];

  const int wg = blockIdx.x;
  const int vv = (wg & 7) * 64 + (wg >> 3);    // XCD swizzle (512 % 8 == 0, bijective)
  const int bh = vv >> 5, qc = vv & 31;        // 32 query-chunks of 128 per bh
  const int b = bh >> 3, h = bh & 7;
  const int tid = threadIdx.x;
  const int wid = tid >> 6, lane = tid & 63;
  const int qwv = wid & 7;                     // query-wave id (0..7)
  const int kh = wid >> 3;                     // key half: 0 -> tiles 0-4, 1 -> tiles 5-8
  const int g = lane >> 4, q16 = lane & 15;
  const int qb = qc * 128;
  const int wb = qb - 128;
  const int qw = qb + qwv * 16;                // this wave's 16 queries
  const int qg = qw + q16;

  const f16* Kb_g = K + (size_t)bh * S_LEN * HDIM;
  const f16* Vb_g = V + (size_t)bh * S_LEN * HDIM;

#pragma unroll
  for (int rd = 0; rd < 3; ++rd) {
    const int idx = rd * 1024 + tid;
    const int r = idx >> 3, sl = idx & 7;
    const int key = min(max(wb + r, 0), S_LEN - 1); // clamped rows masked in compute
    int4 kvv = *(const int4*)(Kb_g + (size_t)key * HDIM + sl * 8);
    *(int4*)(smem + r * 128 + ((sl ^ (r & 7)) << 4)) = kvv;
  }
#pragma unroll
  for (int rd = 0; rd < 3; ++rd) {
    const int idx = rd * 1024 + tid;
    const int r = idx >> 3, c8 = (idx & 7) * 8;
    const int key = min(max(wb + r, 0), S_LEN - 1);
    int4 vvv = *(const int4*)(Vb_g + (size_t)key * HDIM + c8);
    *(int4*)(smem + VSOFF + (c8 >> 4) * 12288 + (r >> 2) * 128 + (r & 3) * 32 + ((c8 & 8) << 1)) = vvv;
  }
  __syncthreads();

  const f16* Qb = Q + ((size_t)bh * S_LEN + qw) * HDIM;
  f16x8 qf0 = *(const f16x8*)(Qb + q16 * HDIM + 8 * g);
  f16x8 qf1 = *(const f16x8*)(Qb + q16 * HDIM + 32 + 8 * g);

  f32x4 zero = {0.f, 0.f, 0.f, 0.f};
  f32x4 o[4];
#pragma unroll
  for (int dt = 0; dt < 4; dt++) o[dt] = zero;
  float m_run = 0.f;   // static base; vote-guarded rescale
  float l_run = 0.f;

  const unsigned troff = (unsigned)(g * 128 + q16 * 8);

  auto do_tile = [&](int t) {
    const int kAp = qwv * 16 + 32 * t;
    const int kBp = kAp + 16;            // may be 384 (qwv=7,t=8): in-smem garbage, fully masked
    const int rrA = kAp + q16;
    const int rrB = kBp + q16;
    f16x8 ka0 = *(const f16x8*)(smem + rrA * 128 + (((g    ) ^ (rrA & 7)) << 4));
    f16x8 ka1 = *(const f16x8*)(smem + rrA * 128 + (((g + 4) ^ (rrA & 7)) << 4));
    f16x8 kb0 = *(const f16x8*)(smem + rrB * 128 + (((g    ) ^ (rrB & 7)) << 4));
    f16x8 kb1 = *(const f16x8*)(smem + rrB * 128 + (((g + 4) ^ (rrB & 7)) << 4));

    f32x4 sA = zero, sB = zero;
    __builtin_amdgcn_s_setprio(1);
    sA = __builtin_amdgcn_mfma_f32_16x16x32_f16(ka0, qf0, sA, 0, 0, 0);
    sA = __builtin_amdgcn_mfma_f32_16x16x32_f16(ka1, qf1, sA, 0, 0, 0);
    sB = __builtin_amdgcn_mfma_f32_16x16x32_f16(kb0, qf0, sB, 0, 0, 0);
    sB = __builtin_amdgcn_mfma_f32_16x16x32_f16(kb1, qf1, sB, 0, 0, 0);
    __builtin_amdgcn_s_setprio(0);

    float sv[8];
    float mx = -INFINITY;
#pragma unroll
    for (int i = 0; i < 4; i++) {
      const int kgA = wb + kAp + 4 * g + i;
      const int kgB = wb + kBp + 4 * g + i;
      const bool okA = ((unsigned)(kgA - qg + 128) <= 256u) && ((unsigned)kgA < S_LEN);
      const bool okB = ((unsigned)(kgB - qg + 128) <= 256u) && ((unsigned)kgB < S_LEN);
      sv[i]     = okA ? sA[i] : -INFINITY;
      sv[i + 4] = okB ? sB[i] : -INFINITY;
      mx = fmaxf(mx, fmaxf(sv[i], sv[i + 4]));
    }

    float pA[4], pB[4];
#pragma unroll
    for (int i = 0; i < 4; i++) {
      pA[i] = EXP2F((sv[i] - m_run) * LOG2E);
      pB[i] = EXP2F((sv[i + 4] - m_run) * LOG2E);
    }

    if (__builtin_expect(!__all(mx - m_run <= 8.f), 0)) {
      float mxq = fmaxf(mx, __shfl_xor(mx, 16));
      mxq = fmaxf(mxq, __shfl_xor(mxq, 32));
      const float mnew = fmaxf(m_run, mxq);
      const float resc = EXP2F((m_run - mnew) * LOG2E);
#pragma unroll
      for (int i = 0; i < 4; i++) { pA[i] *= resc; pB[i] *= resc; }
      l_run *= resc;
      float ri[4];
#pragma unroll
      for (int i = 0; i < 4; i++) ri[i] = __shfl(resc, 4 * g + i);
#pragma unroll
      for (int dt = 0; dt < 4; dt++)
#pragma unroll
        for (int i = 0; i < 4; i++) o[dt][i] *= ri[i];
      m_run = mnew;
    }

    f16x4 pfA, pfB;
#pragma unroll
    for (int i = 0; i < 4; i++) {
      l_run += pA[i] + pB[i];
      pfA[i] = (f16)pA[i];
      pfB[i] = (f16)pB[i];
    }

    const int kcA = kAp;
    const int kcB = min(kBp, 368);   // block index <= 95; clamped tiles fully masked
    f16x4 bA[4], bB[4];
#pragma unroll
    for (int dt = 0; dt < 4; ++dt) {
      unsigned aA = (unsigned)(uintptr_t)(smem + VSOFF + dt * 12288 + (kcA >> 2) * 128) + troff;
      unsigned aB = (unsigned)(uintptr_t)(smem + VSOFF + dt * 12288 + (kcB >> 2) * 128) + troff;
      asm volatile("ds_read_b64_tr_b16 %0, %1" : "=v"(bA[dt]) : "v"(aA));
      asm volatile("ds_read_b64_tr_b16 %0, %1" : "=v"(bB[dt]) : "v"(aB));
    }
    asm volatile("s_waitcnt lgkmcnt(0)" ::: "memory");
    __builtin_amdgcn_sched_barrier(0);

    __builtin_amdgcn_s_setprio(1);
#pragma unroll
    for (int dt = 0; dt < 4; dt++) {
      o[dt] = __builtin_amdgcn_mfma_f32_16x16x16f16(pfA, bA[dt], o[dt], 0, 0, 0);
      o[dt] = __builtin_amdgcn_mfma_f32_16x16x16f16(pfB, bB[dt], o[dt], 0, 0, 0);
    }
    __builtin_amdgcn_s_setprio(0);
  };

  if (kh == 0) {
#pragma unroll
    for (int t = 0; t < 5; ++t) do_tile(t);
  } else {
#pragma unroll
    for (int t = 5; t < 9; ++t) do_tile(t);
  }

  l_run += __shfl_xor(l_run, 16);
  l_run += __shfl_xor(l_run, 32);

  // ---- split-K merge ----
  float* oS = (float*)smem;                    // [8][64][16] f32 = 32 KB
  float* lS = (float*)(smem + 32768);          // [8][64]
  float* mS = (float*)(smem + 34816);          // [8][64]
  __syncthreads();   // all waves done reading K/V LDS
  if (kh == 1) {
#pragma unroll
    for (int dt = 0; dt < 4; dt++)
#pragma unroll
      for (int i = 0; i < 4; i++)
        oS[(qwv * 64 + lane) * 16 + dt * 4 + i] = o[dt][i];
    lS[qwv * 64 + lane] = l_run;
    mS[qwv * 64 + lane] = m_run;
  }
  __syncthreads();   // publish visible
  if (kh == 0) {
    const float mB = mS[qwv * 64 + lane];
    const float lB = lS[qwv * 64 + lane];
    const float m = fmaxf(m_run, mB);
    const float fA = EXP2F((m_run - m) * LOG2E);
    const float fB = EXP2F((mB - m) * LOG2E);
    const float linv = 1.f / (l_run * fA + lB * fB);
    const float aA = fA * linv, aB = fB * linv;   // per query q16
    float aAi[4], aBi[4];
#pragma unroll
    for (int i = 0; i < 4; i++) {
      aAi[i] = __shfl(aA, 4 * g + i);             // per query 4g+i
      aBi[i] = __shfl(aB, 4 * g + i);
    }
    float* st = (float*)(smem + VSOFF) + qwv * 1024;   // 8 x 4 KB
#pragma unroll
    for (int dt = 0; dt < 4; dt++)
#pragma unroll
      for (int i = 0; i < 4; i++) {
        const float ov = o[dt][i] * aAi[i] + oS[(qwv * 64 + lane) * 16 + dt * 4 + i] * aBi[i];
        st[(4 * g + i) * 64 + dt * 16 + q16] = ov;
      }
    const int r = lane >> 2, c0 = (lane & 3) * 16;
    const float* sp = st + r * 64 + c0;
    f16x8 h0, h1;
#pragma unroll
    for (int j = 0; j < 8; j++) { h0[j] = (f16)sp[j]; h1[j] = (f16)sp[8 + j]; }
    f16* dst = O + ((size_t)b * S_LEN + qw + r) * EMB + h * HDIM + c0;
    *(f16x8*)dst = h0;
    *(f16x8*)(dst + 8) = h1;
  }
}

// ---------------- launch ----------------
extern "C" void kernel_launch(void* const* d_in, const int* in_sizes, int n_in,
                              void* d_out, int out_size, void* d_ws, size_t ws_size,
                              hipStream_t stream) {
  const float* x     = (const float*)d_in[0];
  const float* w_qkv = (const float*)d_in[1];
  const float* b_qkv = (const float*)d_in[2];
  const float* w_o   = (const float*)d_in[3];
  const float* b_o   = (const float*)d_in[4];
  float* out = (float*)d_out;

  char* ws = (char*)d_ws;
  f16* wqkvt = (f16*)(ws + 8388608);       // [1536][512]        1.5 MiB
  f16* wot   = (f16*)(ws + 9961472);       // [512][512]         0.5 MiB
  f16* Qs    = (f16*)(ws + 10485760);      // [16][4096][64]     8 MiB
  f16* Ks    = (f16*)(ws + 18874368);      // [16][4096][64]     8 MiB
  f16* Vs    = (f16*)(ws + 27262976);      // [16][4096][64]     8 MiB (row-major)
  f16* attn  = (f16*)(ws + 35651584);      // [8192][512]        8 MiB

  prep_kernel<<<256, 256, 0, stream>>>(w_qkv, wqkvt, w_o, wot);
  gemm_bt_kernel<0, 128><<<dim3(64, 12), 256, 0, stream>>>((const void*)x, wqkvt, b_qkv,
                                                           Qs, Ks, Vs, (float*)nullptr, 8192, 1536);
  attn_kernel<<<512, 1024, 0, stream>>>(Qs, Ks, Vs, attn);
  gemm_bt_kernel<1, 64><<<dim3(64, 8), 256, 0, stream>>>((const void*)attn, wot, b_o,
                                                         (f16*)nullptr, (f16*)nullptr, (f16*)nullptr,
                                                         out, 8192, 512);
}

// Round 18
// 64.240 us; speedup vs baseline: 4.2242x; 1.0316x over previous
//
#include <hip/hip_runtime.h>
#include <hip/hip_bf16.h>
#include <math.h>

typedef _Float16 f16;
typedef __attribute__((ext_vector_type(8))) _Float16 f16x8;
typedef __attribute__((ext_vector_type(4))) _Float16 f16x4;
typedef __attribute__((ext_vector_type(4))) float f32x4;

#define S_LEN 4096
#define NHEAD 8
#define HDIM 64
#define EMB 512
#define KDIM 512
#define LOG2E 1.4426950408889634f

#if __has_builtin(__builtin_amdgcn_exp2f)
#define EXP2F(x) __builtin_amdgcn_exp2f(x)
#else
#define EXP2F(x) exp2f(x)
#endif

// direct HBM->LDS 16B copy: lds dest = wave-uniform base (+ lane*16 by HW),
// global src is per-lane. CK-style addrspace casts (flat->AS3 = low-32 trunc).
__device__ __forceinline__ void g2l16(const void* g, void* l) {
  __builtin_amdgcn_global_load_lds(
      reinterpret_cast<const __attribute__((address_space(1))) unsigned int*>(
          reinterpret_cast<uintptr_t>(g)),
      reinterpret_cast<__attribute__((address_space(3))) unsigned int*>(
          static_cast<unsigned int>(reinterpret_cast<uintptr_t>(l))),
      16, 0, 0);
}

// ---------------- fused prep: x cast (8 f32/thread) + weight transposes ----------------
// blocks [0,2048): cast x f32->f16, 8 elems/thread (2x float4 -> one 16B f16x8 store)
// blocks [2048,2240): transpose w_qkv 512x1536 -> [1536][512] f16  (24x8 tiles)
// blocks [2240,2304): transpose w_o   512x512  -> [512][512]  f16  (8x8 tiles)
__global__ __launch_bounds__(256) void prep_kernel(
    const float* __restrict__ x, f16* __restrict__ xb,
    const float* __restrict__ w_qkv, f16* __restrict__ wqkvt,
    const float* __restrict__ w_o, f16* __restrict__ wot) {
  __shared__ f16 tile[64][65];  // +1 pad: column reads conflict-free
  const int bid = blockIdx.x;
  const int tid = threadIdx.x;
  if (bid < 2048) {
    const int i = (bid * 256 + tid) * 8;
    float4 v0 = *(const float4*)(x + i);
    float4 v1 = *(const float4*)(x + i + 4);
    f16x8 o = { (f16)v0.x, (f16)v0.y, (f16)v0.z, (f16)v0.w,
                (f16)v1.x, (f16)v1.y, (f16)v1.z, (f16)v1.w };
    *(f16x8*)(xb + i) = o;
    return;
  }
  const float* in;
  f16* out;
  int R, C, c0, r0;
  if (bid < 2240) {
    const int t = bid - 2048;
    in = w_qkv; out = wqkvt; R = 512; C = 1536;
    c0 = (t % 24) * 64; r0 = (t / 24) * 64;
  } else {
    const int t = bid - 2240;
    in = w_o; out = wot; R = 512; C = 512;
    c0 = (t & 7) * 64; r0 = (t >> 3) * 64;
  }
#pragma unroll
  for (int i = 0; i < 16; ++i) {
    const int idx = i * 256 + tid;
    const int lr = idx >> 6, lc = idx & 63;
    tile[lr][lc] = (f16)in[(size_t)(r0 + lr) * C + (c0 + lc)];  // coalesced read
  }
  __syncthreads();
#pragma unroll
  for (int i = 0; i < 16; ++i) {
    const int idx = i * 256 + tid;
    const int lc = idx >> 6, lr = idx & 63;
    out[(size_t)(c0 + lc) * R + (r0 + lr)] = tile[lr][lc];      // coalesced write
  }
}

// ---------------- GEMM: C[M][N] = A[M][K] * Bt[N][K]^T + bias ----------------
// BK=32, linear LDS, gload_lds staging, 2-barrier loop (m97 form).
// MODE 0: epilogue bounces C through LDS -> coalesced f16x8 scatter to Q/K/V.
// MODE 1: direct f32 C+bias stores.
#define TM 128
#define TK 32

template<int MODE, int TN>
__global__ __launch_bounds__(256) void gemm_bt_kernel(
    const f16* __restrict__ A, const f16* __restrict__ Bt, const float* __restrict__ bias,
    f16* __restrict__ Qo, f16* __restrict__ Ko, f16* __restrict__ Vo,
    float* __restrict__ Co, int M, int N) {
  constexpr int JN = TN / 32;    // B-frags / acc cols per wave
  constexpr int BCH = TN / 64;   // B staging chunks per wave
  constexpr int SMEMSZ = (MODE == 0) ? (128 * 136 * 2) : (8192 + TN * TK * 2);
  __shared__ __align__(16) char smem[SMEMSZ];
  f16 (*As)[TK] = (f16 (*)[TK])smem;             // [TM][TK], 8 KB
  f16 (*Bs)[TK] = (f16 (*)[TK])(smem + 8192);    // [TN][TK]
  const int m0 = blockIdx.x * TM, n0 = blockIdx.y * TN;
  const int tid = threadIdx.x;
  const int lane = tid & 63, wid = tid >> 6;
  const int wr = wid >> 1, wc = wid & 1;
  const int g = lane >> 4, q16 = lane & 15;

  // staging geometry: chunk = 16 rows = 1024 B; lane l -> row l>>2, 16B slot l&3.
  const int srow = lane >> 2;
  const int skof = (lane & 3) * 8;
  const f16* Ag[2]; char* Al[2];
#pragma unroll
  for (int cb = 0; cb < 2; ++cb) {
    const int ch = wid * 2 + cb;
    Ag[cb] = A + (size_t)(m0 + ch * 16 + srow) * KDIM + skof;
    Al[cb] = (char*)As + ch * 1024;
  }
  const f16* Bg[BCH]; char* Bl[BCH];
#pragma unroll
  for (int cb = 0; cb < BCH; ++cb) {
    const int ch = wid * BCH + cb;
    Bg[cb] = Bt + (size_t)(n0 + ch * 16 + srow) * KDIM + skof;
    Bl[cb] = (char*)Bs + ch * 1024;
  }

  f32x4 zero = {0.f, 0.f, 0.f, 0.f};
  f32x4 acc[4][JN];
#pragma unroll
  for (int i = 0; i < 4; i++)
#pragma unroll
    for (int j = 0; j < JN; j++) acc[i][j] = zero;

  for (int kk = 0; kk < KDIM; kk += TK) {
    g2l16(Ag[0] + kk, Al[0]);
    g2l16(Ag[1] + kk, Al[1]);
#pragma unroll
    for (int cb = 0; cb < BCH; ++cb) g2l16(Bg[cb] + kk, Bl[cb]);
    __syncthreads();   // drains vmcnt (gload_lds) + joins waves
    f16x8 af[4], bfr[JN];
#pragma unroll
    for (int i = 0; i < 4; i++) af[i] = *(const f16x8*)&As[wr * 64 + i * 16 + q16][8 * g];
#pragma unroll
    for (int j = 0; j < JN; j++) bfr[j] = *(const f16x8*)&Bs[wc * (TN / 2) + j * 16 + q16][8 * g];
#pragma unroll
    for (int i = 0; i < 4; i++)
#pragma unroll
      for (int j = 0; j < JN; j++)
        acc[i][j] = __builtin_amdgcn_mfma_f32_16x16x32_f16(af[i], bfr[j], acc[i][j], 0, 0, 0);
    __syncthreads();   // all ds_reads done before next-iter staging overwrites
  }

  if (MODE == 1) {
#pragma unroll
    for (int i = 0; i < 4; i++)
#pragma unroll
      for (int j = 0; j < JN; j++) {
        const int n = n0 + wc * (TN / 2) + j * 16 + q16;
        const float bs = bias[n];
        const int mbase = m0 + wr * 64 + i * 16 + 4 * g;
#pragma unroll
        for (int r = 0; r < 4; r++) Co[(size_t)(mbase + r) * N + n] = acc[i][j][r] + bs;
      }
  } else {
    // ---- LDS-bounce epilogue: acc(+bias,+Q-scale) -> Cs f16 -> coalesced 16B scatter ----
    f16 (*Cs)[136] = (f16 (*)[136])smem;   // aliases As/Bs (dead after final barrier)
#pragma unroll
    for (int i = 0; i < 4; i++)
#pragma unroll
      for (int j = 0; j < JN; j++) {
        const int n = n0 + wc * (TN / 2) + j * 16 + q16;
        const float bs = bias[n];
        const int rr_n = n % 192;                         // section uniform per (i,j)
        const float scale = (rr_n < 64) ? 0.125f : 1.0f;  // Q pre-scaled by 1/8
        const int mrow = wr * 64 + i * 16 + 4 * g;
        const int ncol = wc * (TN / 2) + j * 16 + q16;
#pragma unroll
        for (int r = 0; r < 4; r++)
          Cs[mrow + r][ncol] = (f16)((acc[i][j][r] + bs) * scale);
      }
    __syncthreads();
    const int cc = tid & 15;
    const int nn = n0 + 8 * cc;
    const int hh = nn / 192;
    const int rr = nn - 192 * hh;
    f16* base = (rr < 64) ? Qo : (rr < 128) ? Ko : Vo;
    const int d0 = rr & 63;
#pragma unroll
    for (int it = 0; it < 8; ++it) {
      const int m = (tid >> 4) + 16 * it;
      f16x8 v = *(const f16x8*)&Cs[m][8 * cc];
      const int mglob = m0 + m;
      const int b = mglob >> 12, s = mglob & (S_LEN - 1);
      const size_t bh = (size_t)b * NHEAD + hh;
      *(f16x8*)(base + (bh * S_LEN + s) * HDIM + d0) = v;
    }
  }
}

// ---------------- sliding-window flash attention (LDS window, split-K, 16 waves) ----------------
#define VSOFF 49152

__global__ __launch_bounds__(1024) void attn_kernel(
    const f16* __restrict__ Q, const f16* __restrict__ K,
    const f16* __restrict__ V, f16* __restrict__ O) {
  __shared__ __align__(16) char smem[98304];

  const int wg = blockIdx.x;
  const int vv = (wg & 7) * 64 + (wg >> 3);    // XCD swizzle (512 % 8 == 0, bijective)
  const int bh = vv >> 5, qc = vv & 31;        // 32 query-chunks of 128 per bh
  const int b = bh >> 3, h = bh & 7;
  const int tid = threadIdx.x;
  const int wid = tid >> 6, lane = tid & 63;
  const int qwv = wid & 7;                     // query-wave id (0..7)
  const int kh = wid >> 3;                     // key half: 0 -> tiles 0-4, 1 -> tiles 5-8
  const int g = lane >> 4, q16 = lane & 15;
  const int qb = qc * 128;
  const int wb = qb - 128;
  const int qw = qb + qwv * 16;                // this wave's 16 queries
  const int qg = qw + q16;

  const f16* Kb_g = K + (size_t)bh * S_LEN * HDIM;
  const f16* Vb_g = V + (size_t)bh * S_LEN * HDIM;

#pragma unroll
  for (int rd = 0; rd < 3; ++rd) {
    const int idx = rd * 1024 + tid;
    const int r = idx >> 3, sl = idx & 7;
    const int key = min(max(wb + r, 0), S_LEN - 1); // clamped rows masked in compute
    int4 kvv = *(const int4*)(Kb_g + (size_t)key * HDIM + sl * 8);
    *(int4*)(smem + r * 128 + ((sl ^ (r & 7)) << 4)) = kvv;
  }
#pragma unroll
  for (int rd = 0; rd < 3; ++rd) {
    const int idx = rd * 1024 + tid;
    const int r = idx >> 3, c8 = (idx & 7) * 8;
    const int key = min(max(wb + r, 0), S_LEN - 1);
    int4 vvv = *(const int4*)(Vb_g + (size_t)key * HDIM + c8);
    *(int4*)(smem + VSOFF + (c8 >> 4) * 12288 + (r >> 2) * 128 + (r & 3) * 32 + ((c8 & 8) << 1)) = vvv;
  }
  __syncthreads();

  const f16* Qb = Q + ((size_t)bh * S_LEN + qw) * HDIM;
  f16x8 qf0 = *(const f16x8*)(Qb + q16 * HDIM + 8 * g);
  f16x8 qf1 = *(const f16x8*)(Qb + q16 * HDIM + 32 + 8 * g);

  f32x4 zero = {0.f, 0.f, 0.f, 0.f};
  f32x4 o[4];
#pragma unroll
  for (int dt = 0; dt < 4; dt++) o[dt] = zero;
  float m_run = 0.f;   // static base; vote-guarded rescale
  float l_run = 0.f;

  const unsigned troff = (unsigned)(g * 128 + q16 * 8);

  auto do_tile = [&](int t) {
    const int kAp = qwv * 16 + 32 * t;
    const int kBp = kAp + 16;            // may be 384 (qwv=7,t=8): in-smem garbage, fully masked
    const int rrA = kAp + q16;
    const int rrB = kBp + q16;
    f16x8 ka0 = *(const f16x8*)(smem + rrA * 128 + (((g    ) ^ (rrA & 7)) << 4));
    f16x8 ka1 = *(const f16x8*)(smem + rrA * 128 + (((g + 4) ^ (rrA & 7)) << 4));
    f16x8 kb0 = *(const f16x8*)(smem + rrB * 128 + (((g    ) ^ (rrB & 7)) << 4));
    f16x8 kb1 = *(const f16x8*)(smem + rrB * 128 + (((g + 4) ^ (rrB & 7)) << 4));

    f32x4 sA = zero, sB = zero;
    __builtin_amdgcn_s_setprio(1);
    sA = __builtin_amdgcn_mfma_f32_16x16x32_f16(ka0, qf0, sA, 0, 0, 0);
    sA = __builtin_amdgcn_mfma_f32_16x16x32_f16(ka1, qf1, sA, 0, 0, 0);
    sB = __builtin_amdgcn_mfma_f32_16x16x32_f16(kb0, qf0, sB, 0, 0, 0);
    sB = __builtin_amdgcn_mfma_f32_16x16x32_f16(kb1, qf1, sB, 0, 0, 0);
    __builtin_amdgcn_s_setprio(0);

    float sv[8];
    float mx = -INFINITY;
#pragma unroll
    for (int i = 0; i < 4; i++) {
      const int kgA = wb + kAp + 4 * g + i;
      const int kgB = wb + kBp + 4 * g + i;
      const bool okA = ((unsigned)(kgA - qg + 128) <= 256u) && ((unsigned)kgA < S_LEN);
      const bool okB = ((unsigned)(kgB - qg + 128) <= 256u) && ((unsigned)kgB < S_LEN);
      sv[i]     = okA ? sA[i] : -INFINITY;
      sv[i + 4] = okB ? sB[i] : -INFINITY;
      mx = fmaxf(mx, fmaxf(sv[i], sv[i + 4]));
    }

    float pA[4], pB[4];
#pragma unroll
    for (int i = 0; i < 4; i++) {
      pA[i] = EXP2F((sv[i] - m_run) * LOG2E);
      pB[i] = EXP2F((sv[i + 4] - m_run) * LOG2E);
    }

    if (__builtin_expect(!__all(mx - m_run <= 8.f), 0)) {
      float mxq = fmaxf(mx, __shfl_xor(mx, 16));
      mxq = fmaxf(mxq, __shfl_xor(mxq, 32));
      const float mnew = fmaxf(m_run, mxq);
      const float resc = EXP2F((m_run - mnew) * LOG2E);
#pragma unroll
      for (int i = 0; i < 4; i++) { pA[i] *= resc; pB[i] *= resc; }
      l_run *= resc;
      float ri[4];
#pragma unroll
      for (int i = 0; i < 4; i++) ri[i] = __shfl(resc, 4 * g + i);
#pragma unroll
      for (int dt = 0; dt < 4; dt++)
#pragma unroll
        for (int i = 0; i < 4; i++) o[dt][i] *= ri[i];
      m_run = mnew;
    }

    f16x4 pfA, pfB;
#pragma unroll
    for (int i = 0; i < 4; i++) {
      l_run += pA[i] + pB[i];
      pfA[i] = (f16)pA[i];
      pfB[i] = (f16)pB[i];
    }

    const int kcA = kAp;
    const int kcB = min(kBp, 368);   // block index <= 95; clamped tiles fully masked
    f16x4 bA[4], bB[4];
#pragma unroll
    for (int dt = 0; dt < 4; ++dt) {
      unsigned aA = (unsigned)(uintptr_t)(smem + VSOFF + dt * 12288 + (kcA >> 2) * 128) + troff;
      unsigned aB = (unsigned)(uintptr_t)(smem + VSOFF + dt * 12288 + (kcB >> 2) * 128) + troff;
      asm volatile("ds_read_b64_tr_b16 %0, %1" : "=v"(bA[dt]) : "v"(aA));
      asm volatile("ds_read_b64_tr_b16 %0, %1" : "=v"(bB[dt]) : "v"(aB));
    }
    asm volatile("s_waitcnt lgkmcnt(0)" ::: "memory");
    __builtin_amdgcn_sched_barrier(0);

    __builtin_amdgcn_s_setprio(1);
#pragma unroll
    for (int dt = 0; dt < 4; dt++) {
      o[dt] = __builtin_amdgcn_mfma_f32_16x16x16f16(pfA, bA[dt], o[dt], 0, 0, 0);
      o[dt] = __builtin_amdgcn_mfma_f32_16x16x16f16(pfB, bB[dt], o[dt], 0, 0, 0);
    }
    __builtin_amdgcn_s_setprio(0);
  };

  if (kh == 0) {
#pragma unroll
    for (int t = 0; t < 5; ++t) do_tile(t);
  } else {
#pragma unroll
    for (int t = 5; t < 9; ++t) do_tile(t);
  }

  l_run += __shfl_xor(l_run, 16);
  l_run += __shfl_xor(l_run, 32);

  // ---- split-K merge ----
  float* oS = (float*)smem;                    // [8][64][16] f32 = 32 KB
  float* lS = (float*)(smem + 32768);          // [8][64]
  float* mS = (float*)(smem + 34816);          // [8][64]
  __syncthreads();   // all waves done reading K/V LDS
  if (kh == 1) {
#pragma unroll
    for (int dt = 0; dt < 4; dt++)
#pragma unroll
      for (int i = 0; i < 4; i++)
        oS[(qwv * 64 + lane) * 16 + dt * 4 + i] = o[dt][i];
    lS[qwv * 64 + lane] = l_run;
    mS[qwv * 64 + lane] = m_run;
  }
  __syncthreads();   // publish visible
  if (kh == 0) {
    const float mB = mS[qwv * 64 + lane];
    const float lB = lS[qwv * 64 + lane];
    const float m = fmaxf(m_run, mB);
    const float fA = EXP2F((m_run - m) * LOG2E);
    const float fB = EXP2F((mB - m) * LOG2E);
    const float linv = 1.f / (l_run * fA + lB * fB);
    const float aA = fA * linv, aB = fB * linv;   // per query q16
    float aAi[4], aBi[4];
#pragma unroll
    for (int i = 0; i < 4; i++) {
      aAi[i] = __shfl(aA, 4 * g + i);             // per query 4g+i
      aBi[i] = __shfl(aB, 4 * g + i);
    }
    float* st = (float*)(smem + VSOFF) + qwv * 1024;   // 8 x 4 KB
#pragma unroll
    for (int dt = 0; dt < 4; dt++)
#pragma unroll
      for (int i = 0; i < 4; i++) {
        const float ov = o[dt][i] * aAi[i] + oS[(qwv * 64 + lane) * 16 + dt * 4 + i] * aBi[i];
        st[(4 * g + i) * 64 + dt * 16 + q16] = ov;
      }
    const int r = lane >> 2, c0 = (lane & 3) * 16;
    const float* sp = st + r * 64 + c0;
    f16x8 h0, h1;
#pragma unroll
    for (int j = 0; j < 8; j++) { h0[j] = (f16)sp[j]; h1[j] = (f16)sp[8 + j]; }
    f16* dst = O + ((size_t)b * S_LEN + qw + r) * EMB + h * HDIM + c0;
    *(f16x8*)dst = h0;
    *(f16x8*)(dst + 8) = h1;
  }
}

// ---------------- launch ----------------
extern "C" void kernel_launch(void* const* d_in, const int* in_sizes, int n_in,
                              void* d_out, int out_size, void* d_ws, size_t ws_size,
                              hipStream_t stream) {
  const float* x     = (const float*)d_in[0];
  const float* w_qkv = (const float*)d_in[1];
  const float* b_qkv = (const float*)d_in[2];
  const float* w_o   = (const float*)d_in[3];
  const float* b_o   = (const float*)d_in[4];
  float* out = (float*)d_out;

  char* ws = (char*)d_ws;
  f16* xb    = (f16*)(ws);                 // [8192][512]        8.0 MiB
  f16* wqkvt = (f16*)(ws + 8388608);       // [1536][512]        1.5 MiB
  f16* wot   = (f16*)(ws + 9961472);       // [512][512]         0.5 MiB
  f16* Qs    = (f16*)(ws + 10485760);      // [16][4096][64]     8 MiB
  f16* Ks    = (f16*)(ws + 18874368);      // [16][4096][64]     8 MiB
  f16* Vs    = (f16*)(ws + 27262976);      // [16][4096][64]     8 MiB (row-major)
  f16* attn  = (f16*)(ws + 35651584);      // [8192][512]        8 MiB

  prep_kernel<<<2304, 256, 0, stream>>>(x, xb, w_qkv, wqkvt, w_o, wot);
  gemm_bt_kernel<0, 128><<<dim3(64, 12), 256, 0, stream>>>(xb, wqkvt, b_qkv, Qs, Ks, Vs,
                                                           (float*)nullptr, 8192, 1536);
  attn_kernel<<<512, 1024, 0, stream>>>(Qs, Ks, Vs, attn);
  gemm_bt_kernel<1, 64><<<dim3(64, 8), 256, 0, stream>>>(attn, wot, b_o,
                                                         (f16*)nullptr, (f16*)nullptr, (f16*)nullptr,
                                                         out, 8192, 512);
}

// Round 19
// 63.491 us; speedup vs baseline: 4.2740x; 1.0118x over previous
//
#include <hip/hip_runtime.h>
#include <hip/hip_bf16.h>
#include <math.h>

typedef _Float16 f16;
typedef __attribute__((ext_vector_type(8))) _Float16 f16x8;
typedef __attribute__((ext_vector_type(4))) _Float16 f16x4;
typedef __attribute__((ext_vector_type(4))) float f32x4;

#define S_LEN 4096
#define NHEAD 8
#define HDIM 64
#define EMB 512
#define KDIM 512
#define LOG2E 1.4426950408889634f

#if __has_builtin(__builtin_amdgcn_exp2f)
#define EXP2F(x) __builtin_amdgcn_exp2f(x)
#else
#define EXP2F(x) exp2f(x)
#endif

// direct HBM->LDS 16B copy: lds dest = wave-uniform base (+ lane*16 by HW),
// global src is per-lane. CK-style addrspace casts (flat->AS3 = low-32 trunc).
__device__ __forceinline__ void g2l16(const void* g, void* l) {
  __builtin_amdgcn_global_load_lds(
      reinterpret_cast<const __attribute__((address_space(1))) unsigned int*>(
          reinterpret_cast<uintptr_t>(g)),
      reinterpret_cast<__attribute__((address_space(3))) unsigned int*>(
          static_cast<unsigned int>(reinterpret_cast<uintptr_t>(l))),
      16, 0, 0);
}

// ---------------- fused prep: x cast (8 f32/thread) + weight transposes ----------------
// blocks [0,2048): cast x f32->f16, 8 elems/thread (2x float4 -> one 16B f16x8 store)
// blocks [2048,2240): transpose w_qkv 512x1536 -> [1536][512] f16  (24x8 tiles)
// blocks [2240,2304): transpose w_o   512x512  -> [512][512]  f16  (8x8 tiles)
__global__ __launch_bounds__(256) void prep_kernel(
    const float* __restrict__ x, f16* __restrict__ xb,
    const float* __restrict__ w_qkv, f16* __restrict__ wqkvt,
    const float* __restrict__ w_o, f16* __restrict__ wot) {
  __shared__ f16 tile[64][65];  // +1 pad: column reads conflict-free
  const int bid = blockIdx.x;
  const int tid = threadIdx.x;
  if (bid < 2048) {
    const int i = (bid * 256 + tid) * 8;
    float4 v0 = *(const float4*)(x + i);
    float4 v1 = *(const float4*)(x + i + 4);
    f16x8 o = { (f16)v0.x, (f16)v0.y, (f16)v0.z, (f16)v0.w,
                (f16)v1.x, (f16)v1.y, (f16)v1.z, (f16)v1.w };
    *(f16x8*)(xb + i) = o;
    return;
  }
  const float* in;
  f16* out;
  int R, C, c0, r0;
  if (bid < 2240) {
    const int t = bid - 2048;
    in = w_qkv; out = wqkvt; R = 512; C = 1536;
    c0 = (t % 24) * 64; r0 = (t / 24) * 64;
  } else {
    const int t = bid - 2240;
    in = w_o; out = wot; R = 512; C = 512;
    c0 = (t & 7) * 64; r0 = (t >> 3) * 64;
  }
#pragma unroll
  for (int i = 0; i < 16; ++i) {
    const int idx = i * 256 + tid;
    const int lr = idx >> 6, lc = idx & 63;
    tile[lr][lc] = (f16)in[(size_t)(r0 + lr) * C + (c0 + lc)];  // coalesced read
  }
  __syncthreads();
#pragma unroll
  for (int i = 0; i < 16; ++i) {
    const int idx = i * 256 + tid;
    const int lc = idx >> 6, lr = idx & 63;
    out[(size_t)(c0 + lc) * R + (r0 + lr)] = tile[lr][lc];      // coalesced write
  }
}

// ---------------- GEMM: C[M][N] = A[M][K] * Bt[N][K]^T + bias ----------------
// BK=32, linear LDS, gload_lds staging, 2-barrier loop (m97 form).
// MODE 0: epilogue bounces C through LDS -> coalesced f16x8 scatter to Q/K/V.
// MODE 1: direct f32 C+bias stores.
#define TM 128
#define TK 32

template<int MODE, int TN>
__global__ __launch_bounds__(256) void gemm_bt_kernel(
    const f16* __restrict__ A, const f16* __restrict__ Bt, const float* __restrict__ bias,
    f16* __restrict__ Qo, f16* __restrict__ Ko, f16* __restrict__ Vo,
    float* __restrict__ Co, int M, int N) {
  constexpr int JN = TN / 32;    // B-frags / acc cols per wave
  constexpr int BCH = TN / 64;   // B staging chunks per wave
  constexpr int SMEMSZ = (MODE == 0) ? (128 * 136 * 2) : (8192 + TN * TK * 2);
  __shared__ __align__(16) char smem[SMEMSZ];
  f16 (*As)[TK] = (f16 (*)[TK])smem;             // [TM][TK], 8 KB
  f16 (*Bs)[TK] = (f16 (*)[TK])(smem + 8192);    // [TN][TK]
  const int m0 = blockIdx.x * TM, n0 = blockIdx.y * TN;
  const int tid = threadIdx.x;
  const int lane = tid & 63, wid = tid >> 6;
  const int wr = wid >> 1, wc = wid & 1;
  const int g = lane >> 4, q16 = lane & 15;

  // staging geometry: chunk = 16 rows = 1024 B; lane l -> row l>>2, 16B slot l&3.
  const int srow = lane >> 2;
  const int skof = (lane & 3) * 8;
  const f16* Ag[2]; char* Al[2];
#pragma unroll
  for (int cb = 0; cb < 2; ++cb) {
    const int ch = wid * 2 + cb;
    Ag[cb] = A + (size_t)(m0 + ch * 16 + srow) * KDIM + skof;
    Al[cb] = (char*)As + ch * 1024;
  }
  const f16* Bg[BCH]; char* Bl[BCH];
#pragma unroll
  for (int cb = 0; cb < BCH; ++cb) {
    const int ch = wid * BCH + cb;
    Bg[cb] = Bt + (size_t)(n0 + ch * 16 + srow) * KDIM + skof;
    Bl[cb] = (char*)Bs + ch * 1024;
  }

  f32x4 zero = {0.f, 0.f, 0.f, 0.f};
  f32x4 acc[4][JN];
#pragma unroll
  for (int i = 0; i < 4; i++)
#pragma unroll
    for (int j = 0; j < JN; j++) acc[i][j] = zero;

  for (int kk = 0; kk < KDIM; kk += TK) {
    g2l16(Ag[0] + kk, Al[0]);
    g2l16(Ag[1] + kk, Al[1]);
#pragma unroll
    for (int cb = 0; cb < BCH; ++cb) g2l16(Bg[cb] + kk, Bl[cb]);
    __syncthreads();   // drains vmcnt (gload_lds) + joins waves
    f16x8 af[4], bfr[JN];
#pragma unroll
    for (int i = 0; i < 4; i++) af[i] = *(const f16x8*)&As[wr * 64 + i * 16 + q16][8 * g];
#pragma unroll
    for (int j = 0; j < JN; j++) bfr[j] = *(const f16x8*)&Bs[wc * (TN / 2) + j * 16 + q16][8 * g];
#pragma unroll
    for (int i = 0; i < 4; i++)
#pragma unroll
      for (int j = 0; j < JN; j++)
        acc[i][j] = __builtin_amdgcn_mfma_f32_16x16x32_f16(af[i], bfr[j], acc[i][j], 0, 0, 0);
    __syncthreads();   // all ds_reads done before next-iter staging overwrites
  }

  if (MODE == 1) {
#pragma unroll
    for (int i = 0; i < 4; i++)
#pragma unroll
      for (int j = 0; j < JN; j++) {
        const int n = n0 + wc * (TN / 2) + j * 16 + q16;
        const float bs = bias[n];
        const int mbase = m0 + wr * 64 + i * 16 + 4 * g;
#pragma unroll
        for (int r = 0; r < 4; r++) Co[(size_t)(mbase + r) * N + n] = acc[i][j][r] + bs;
      }
  } else {
    // ---- LDS-bounce epilogue: acc(+bias,+Q-scale) -> Cs f16 -> coalesced 16B scatter ----
    f16 (*Cs)[136] = (f16 (*)[136])smem;   // aliases As/Bs (dead after final barrier)
#pragma unroll
    for (int i = 0; i < 4; i++)
#pragma unroll
      for (int j = 0; j < JN; j++) {
        const int n = n0 + wc * (TN / 2) + j * 16 + q16;
        const float bs = bias[n];
        const int rr_n = n % 192;                         // section uniform per (i,j)
        const float scale = (rr_n < 64) ? 0.125f : 1.0f;  // Q pre-scaled by 1/8
        const int mrow = wr * 64 + i * 16 + 4 * g;
        const int ncol = wc * (TN / 2) + j * 16 + q16;
#pragma unroll
        for (int r = 0; r < 4; r++)
          Cs[mrow + r][ncol] = (f16)((acc[i][j][r] + bs) * scale);
      }
    __syncthreads();
    const int cc = tid & 15;
    const int nn = n0 + 8 * cc;
    const int hh = nn / 192;
    const int rr = nn - 192 * hh;
    f16* base = (rr < 64) ? Qo : (rr < 128) ? Ko : Vo;
    const int d0 = rr & 63;
#pragma unroll
    for (int it = 0; it < 8; ++it) {
      const int m = (tid >> 4) + 16 * it;
      f16x8 v = *(const f16x8*)&Cs[m][8 * cc];
      const int mglob = m0 + m;
      const int b = mglob >> 12, s = mglob & (S_LEN - 1);
      const size_t bh = (size_t)b * NHEAD + hh;
      *(f16x8*)(base + (bh * S_LEN + s) * HDIM + d0) = v;
    }
  }
}

// ---------------- sliding-window flash attention (LDS window, split-K, 16 waves) ----------------
// Interior blocks (qb in [128,3840], 30/32): tiles 1-7 skip masking entirely —
// proven: offsets d=32t-128 give per-lane |key-query| <= 111 < 128 for t in 1..7,
// and the whole 384-key window is in [0,4096). Only t=0 (chunk A) and t=8 need
// masks. Edge blocks: full masked path (identical to prior rounds).
#define VSOFF 49152

__global__ __launch_bounds__(1024) void attn_kernel(
    const f16* __restrict__ Q, const f16* __restrict__ K,
    const f16* __restrict__ V, f16* __restrict__ O) {
  __shared__ __align__(16) char smem[98304];

  const int wg = blockIdx.x;
  const int vv = (wg & 7) * 64 + (wg >> 3);    // XCD swizzle (512 % 8 == 0, bijective)
  const int bh = vv >> 5, qc = vv & 31;        // 32 query-chunks of 128 per bh
  const int b = bh >> 3, h = bh & 7;
  const int tid = threadIdx.x;
  const int wid = tid >> 6, lane = tid & 63;
  const int qwv = wid & 7;                     // query-wave id (0..7)
  const int kh = wid >> 3;                     // key half: 0 -> tiles 0-4, 1 -> tiles 5-8
  const int g = lane >> 4, q16 = lane & 15;
  const int qb = qc * 128;
  const int wb = qb - 128;
  const int qw = qb + qwv * 16;                // this wave's 16 queries
  const int qg = qw + q16;

  const f16* Kb_g = K + (size_t)bh * S_LEN * HDIM;
  const f16* Vb_g = V + (size_t)bh * S_LEN * HDIM;

#pragma unroll
  for (int rd = 0; rd < 3; ++rd) {
    const int idx = rd * 1024 + tid;
    const int r = idx >> 3, sl = idx & 7;
    const int key = min(max(wb + r, 0), S_LEN - 1); // clamped rows masked in compute
    int4 kvv = *(const int4*)(Kb_g + (size_t)key * HDIM + sl * 8);
    *(int4*)(smem + r * 128 + ((sl ^ (r & 7)) << 4)) = kvv;
  }
#pragma unroll
  for (int rd = 0; rd < 3; ++rd) {
    const int idx = rd * 1024 + tid;
    const int r = idx >> 3, c8 = (idx & 7) * 8;
    const int key = min(max(wb + r, 0), S_LEN - 1);
    int4 vvv = *(const int4*)(Vb_g + (size_t)key * HDIM + c8);
    *(int4*)(smem + VSOFF + (c8 >> 4) * 12288 + (r >> 2) * 128 + (r & 3) * 32 + ((c8 & 8) << 1)) = vvv;
  }
  __syncthreads();

  const f16* Qb = Q + ((size_t)bh * S_LEN + qw) * HDIM;
  f16x8 qf0 = *(const f16x8*)(Qb + q16 * HDIM + 8 * g);
  f16x8 qf1 = *(const f16x8*)(Qb + q16 * HDIM + 32 + 8 * g);

  f32x4 zero = {0.f, 0.f, 0.f, 0.f};
  f32x4 o[4];
#pragma unroll
  for (int dt = 0; dt < 4; dt++) o[dt] = zero;
  float m_run = 0.f;   // static base; vote-guarded rescale
  float l_run = 0.f;

  const unsigned troff = (unsigned)(g * 128 + q16 * 8);

  auto do_tile = [&](int t, bool domask) {
    const int kAp = qwv * 16 + 32 * t;
    const int kBp = kAp + 16;            // may be 384 (qwv=7,t=8): in-smem garbage, fully masked
    const int rrA = kAp + q16;
    const int rrB = kBp + q16;
    f16x8 ka0 = *(const f16x8*)(smem + rrA * 128 + (((g    ) ^ (rrA & 7)) << 4));
    f16x8 ka1 = *(const f16x8*)(smem + rrA * 128 + (((g + 4) ^ (rrA & 7)) << 4));
    f16x8 kb0 = *(const f16x8*)(smem + rrB * 128 + (((g    ) ^ (rrB & 7)) << 4));
    f16x8 kb1 = *(const f16x8*)(smem + rrB * 128 + (((g + 4) ^ (rrB & 7)) << 4));

    f32x4 sA = zero, sB = zero;
    __builtin_amdgcn_s_setprio(1);
    sA = __builtin_amdgcn_mfma_f32_16x16x32_f16(ka0, qf0, sA, 0, 0, 0);
    sA = __builtin_amdgcn_mfma_f32_16x16x32_f16(ka1, qf1, sA, 0, 0, 0);
    sB = __builtin_amdgcn_mfma_f32_16x16x32_f16(kb0, qf0, sB, 0, 0, 0);
    sB = __builtin_amdgcn_mfma_f32_16x16x32_f16(kb1, qf1, sB, 0, 0, 0);
    __builtin_amdgcn_s_setprio(0);

    float sv[8];
    float mx = -INFINITY;
    if (domask) {
#pragma unroll
      for (int i = 0; i < 4; i++) {
        const int kgA = wb + kAp + 4 * g + i;
        const int kgB = wb + kBp + 4 * g + i;
        const bool okA = ((unsigned)(kgA - qg + 128) <= 256u) && ((unsigned)kgA < S_LEN);
        const bool okB = ((unsigned)(kgB - qg + 128) <= 256u) && ((unsigned)kgB < S_LEN);
        sv[i]     = okA ? sA[i] : -INFINITY;
        sv[i + 4] = okB ? sB[i] : -INFINITY;
        mx = fmaxf(mx, fmaxf(sv[i], sv[i + 4]));
      }
    } else {
      // fast path: every (key,query) pair provably inside window and sequence
#pragma unroll
      for (int i = 0; i < 4; i++) {
        sv[i]     = sA[i];
        sv[i + 4] = sB[i];
        mx = fmaxf(mx, fmaxf(sv[i], sv[i + 4]));
      }
    }

    float pA[4], pB[4];
#pragma unroll
    for (int i = 0; i < 4; i++) {
      pA[i] = EXP2F((sv[i] - m_run) * LOG2E);
      pB[i] = EXP2F((sv[i + 4] - m_run) * LOG2E);
    }

    if (__builtin_expect(!__all(mx - m_run <= 8.f), 0)) {
      float mxq = fmaxf(mx, __shfl_xor(mx, 16));
      mxq = fmaxf(mxq, __shfl_xor(mxq, 32));
      const float mnew = fmaxf(m_run, mxq);
      const float resc = EXP2F((m_run - mnew) * LOG2E);
#pragma unroll
      for (int i = 0; i < 4; i++) { pA[i] *= resc; pB[i] *= resc; }
      l_run *= resc;
      float ri[4];
#pragma unroll
      for (int i = 0; i < 4; i++) ri[i] = __shfl(resc, 4 * g + i);
#pragma unroll
      for (int dt = 0; dt < 4; dt++)
#pragma unroll
        for (int i = 0; i < 4; i++) o[dt][i] *= ri[i];
      m_run = mnew;
    }

    f16x4 pfA, pfB;
#pragma unroll
    for (int i = 0; i < 4; i++) {
      l_run += pA[i] + pB[i];
      pfA[i] = (f16)pA[i];
      pfB[i] = (f16)pB[i];
    }

    const int kcA = kAp;
    const int kcB = min(kBp, 368);   // block index <= 95; clamped tiles fully masked
    f16x4 bA[4], bB[4];
#pragma unroll
    for (int dt = 0; dt < 4; ++dt) {
      unsigned aA = (unsigned)(uintptr_t)(smem + VSOFF + dt * 12288 + (kcA >> 2) * 128) + troff;
      unsigned aB = (unsigned)(uintptr_t)(smem + VSOFF + dt * 12288 + (kcB >> 2) * 128) + troff;
      asm volatile("ds_read_b64_tr_b16 %0, %1" : "=v"(bA[dt]) : "v"(aA));
      asm volatile("ds_read_b64_tr_b16 %0, %1" : "=v"(bB[dt]) : "v"(aB));
    }
    asm volatile("s_waitcnt lgkmcnt(0)" ::: "memory");
    __builtin_amdgcn_sched_barrier(0);

    __builtin_amdgcn_s_setprio(1);
#pragma unroll
    for (int dt = 0; dt < 4; dt++) {
      o[dt] = __builtin_amdgcn_mfma_f32_16x16x16f16(pfA, bA[dt], o[dt], 0, 0, 0);
      o[dt] = __builtin_amdgcn_mfma_f32_16x16x16f16(pfB, bB[dt], o[dt], 0, 0, 0);
    }
    __builtin_amdgcn_s_setprio(0);
  };

  const bool interior = (qb >= 128) && (qb <= S_LEN - 256);  // wb>=0 && wb+384<=S_LEN
  if (interior) {
    if (kh == 0) {
      do_tile(0, true);
      do_tile(1, false); do_tile(2, false); do_tile(3, false); do_tile(4, false);
    } else {
      do_tile(5, false); do_tile(6, false); do_tile(7, false);
      do_tile(8, true);
    }
  } else {
    if (kh == 0) {
#pragma unroll
      for (int t = 0; t < 5; ++t) do_tile(t, true);
    } else {
#pragma unroll
      for (int t = 5; t < 9; ++t) do_tile(t, true);
    }
  }

  l_run += __shfl_xor(l_run, 16);
  l_run += __shfl_xor(l_run, 32);

  // ---- split-K merge ----
  float* oS = (float*)smem;                    // [8][64][16] f32 = 32 KB
  float* lS = (float*)(smem + 32768);          // [8][64]
  float* mS = (float*)(smem + 34816);          // [8][64]
  __syncthreads();   // all waves done reading K/V LDS
  if (kh == 1) {
#pragma unroll
    for (int dt = 0; dt < 4; dt++)
#pragma unroll
      for (int i = 0; i < 4; i++)
        oS[(qwv * 64 + lane) * 16 + dt * 4 + i] = o[dt][i];
    lS[qwv * 64 + lane] = l_run;
    mS[qwv * 64 + lane] = m_run;
  }
  __syncthreads();   // publish visible
  if (kh == 0) {
    const float mB = mS[qwv * 64 + lane];
    const float lB = lS[qwv * 64 + lane];
    const float m = fmaxf(m_run, mB);
    const float fA = EXP2F((m_run - m) * LOG2E);
    const float fB = EXP2F((mB - m) * LOG2E);
    const float linv = 1.f / (l_run * fA + lB * fB);
    const float aA = fA * linv, aB = fB * linv;   // per query q16
    float aAi[4], aBi[4];
#pragma unroll
    for (int i = 0; i < 4; i++) {
      aAi[i] = __shfl(aA, 4 * g + i);             // per query 4g+i
      aBi[i] = __shfl(aB, 4 * g + i);
    }
    float* st = (float*)(smem + VSOFF) + qwv * 1024;   // 8 x 4 KB
#pragma unroll
    for (int dt = 0; dt < 4; dt++)
#pragma unroll
      for (int i = 0; i < 4; i++) {
        const float ov = o[dt][i] * aAi[i] + oS[(qwv * 64 + lane) * 16 + dt * 4 + i] * aBi[i];
        st[(4 * g + i) * 64 + dt * 16 + q16] = ov;
      }
    const int r = lane >> 2, c0 = (lane & 3) * 16;
    const float* sp = st + r * 64 + c0;
    f16x8 h0, h1;
#pragma unroll
    for (int j = 0; j < 8; j++) { h0[j] = (f16)sp[j]; h1[j] = (f16)sp[8 + j]; }
    f16* dst = O + ((size_t)b * S_LEN + qw + r) * EMB + h * HDIM + c0;
    *(f16x8*)dst = h0;
    *(f16x8*)(dst + 8) = h1;
  }
}

// ---------------- launch ----------------
extern "C" void kernel_launch(void* const* d_in, const int* in_sizes, int n_in,
                              void* d_out, int out_size, void* d_ws, size_t ws_size,
                              hipStream_t stream) {
  const float* x     = (const float*)d_in[0];
  const float* w_qkv = (const float*)d_in[1];
  const float* b_qkv = (const float*)d_in[2];
  const float* w_o   = (const float*)d_in[3];
  const float* b_o   = (const float*)d_in[4];
  float* out = (float*)d_out;

  char* ws = (char*)d_ws;
  f16* xb    = (f16*)(ws);                 // [8192][512]        8.0 MiB
  f16* wqkvt = (f16*)(ws + 8388608);       // [1536][512]        1.5 MiB
  f16* wot   = (f16*)(ws + 9961472);       // [512][512]         0.5 MiB
  f16* Qs    = (f16*)(ws + 10485760);      // [16][4096][64]     8 MiB
  f16* Ks    = (f16*)(ws + 18874368);      // [16][4096][64]     8 MiB
  f16* Vs    = (f16*)(ws + 27262976);      // [16][4096][64]     8 MiB (row-major)
  f16* attn  = (f16*)(ws + 35651584);      // [8192][512]        8 MiB

  prep_kernel<<<2304, 256, 0, stream>>>(x, xb, w_qkv, wqkvt, w_o, wot);
  gemm_bt_kernel<0, 128><<<dim3(64, 12), 256, 0, stream>>>(xb, wqkvt, b_qkv, Qs, Ks, Vs,
                                                           (float*)nullptr, 8192, 1536);
  attn_kernel<<<512, 1024, 0, stream>>>(Qs, Ks, Vs, attn);
  gemm_bt_kernel<1, 64><<<dim3(64, 8), 256, 0, stream>>>(attn, wot, b_o,
                                                         (f16*)nullptr, (f16*)nullptr, (f16*)nullptr,
                                                         out, 8192, 512);
}

// Round 20
// 63.345 us; speedup vs baseline: 4.2839x; 1.0023x over previous
//
#include <hip/hip_runtime.h>
#include <hip/hip_bf16.h>
#include <math.h>

typedef _Float16 f16;
typedef __attribute__((ext_vector_type(8))) _Float16 f16x8;
typedef __attribute__((ext_vector_type(4))) _Float16 f16x4;
typedef __attribute__((ext_vector_type(4))) float f32x4;

#define S_LEN 4096
#define NHEAD 8
#define HDIM 64
#define EMB 512
#define KDIM 512
#define LOG2E 1.4426950408889634f

#if __has_builtin(__builtin_amdgcn_exp2f)
#define EXP2F(x) __builtin_amdgcn_exp2f(x)
#else
#define EXP2F(x) exp2f(x)
#endif

// direct HBM->LDS 16B copy: lds dest = wave-uniform base (+ lane*16 by HW),
// global src is per-lane. CK-style addrspace casts (flat->AS3 = low-32 trunc).
__device__ __forceinline__ void g2l16(const void* g, void* l) {
  __builtin_amdgcn_global_load_lds(
      reinterpret_cast<const __attribute__((address_space(1))) unsigned int*>(
          reinterpret_cast<uintptr_t>(g)),
      reinterpret_cast<__attribute__((address_space(3))) unsigned int*>(
          static_cast<unsigned int>(reinterpret_cast<uintptr_t>(l))),
      16, 0, 0);
}

// ---------------- fused prep: x cast (8 f32/thread) + weight transposes ----------------
__global__ __launch_bounds__(256) void prep_kernel(
    const float* __restrict__ x, f16* __restrict__ xb,
    const float* __restrict__ w_qkv, f16* __restrict__ wqkvt,
    const float* __restrict__ w_o, f16* __restrict__ wot) {
  __shared__ f16 tile[64][65];  // +1 pad: column reads conflict-free
  const int bid = blockIdx.x;
  const int tid = threadIdx.x;
  if (bid < 2048) {
    const int i = (bid * 256 + tid) * 8;
    float4 v0 = *(const float4*)(x + i);
    float4 v1 = *(const float4*)(x + i + 4);
    f16x8 o = { (f16)v0.x, (f16)v0.y, (f16)v0.z, (f16)v0.w,
                (f16)v1.x, (f16)v1.y, (f16)v1.z, (f16)v1.w };
    *(f16x8*)(xb + i) = o;
    return;
  }
  const float* in;
  f16* out;
  int R, C, c0, r0;
  if (bid < 2240) {
    const int t = bid - 2048;
    in = w_qkv; out = wqkvt; R = 512; C = 1536;
    c0 = (t % 24) * 64; r0 = (t / 24) * 64;
  } else {
    const int t = bid - 2240;
    in = w_o; out = wot; R = 512; C = 512;
    c0 = (t & 7) * 64; r0 = (t >> 3) * 64;
  }
#pragma unroll
  for (int i = 0; i < 16; ++i) {
    const int idx = i * 256 + tid;
    const int lr = idx >> 6, lc = idx & 63;
    tile[lr][lc] = (f16)in[(size_t)(r0 + lr) * C + (c0 + lc)];  // coalesced read
  }
  __syncthreads();
#pragma unroll
  for (int i = 0; i < 16; ++i) {
    const int idx = i * 256 + tid;
    const int lc = idx >> 6, lr = idx & 63;
    out[(size_t)(c0 + lc) * R + (r0 + lr)] = tile[lr][lc];      // coalesced write
  }
}

// ---------------- GEMM: C[M][N] = A[M][K] * Bt[N][K]^T + bias ----------------
// BK=32, linear LDS, gload_lds staging, 2-barrier loop (m97 form).
#define TM 128
#define TK 32

template<int MODE, int TN>
__global__ __launch_bounds__(256) void gemm_bt_kernel(
    const f16* __restrict__ A, const f16* __restrict__ Bt, const float* __restrict__ bias,
    f16* __restrict__ Qo, f16* __restrict__ Ko, f16* __restrict__ Vo,
    float* __restrict__ Co, int M, int N) {
  constexpr int JN = TN / 32;    // B-frags / acc cols per wave
  constexpr int BCH = TN / 64;   // B staging chunks per wave
  constexpr int SMEMSZ = (MODE == 0) ? (128 * 136 * 2) : (8192 + TN * TK * 2);
  __shared__ __align__(16) char smem[SMEMSZ];
  f16 (*As)[TK] = (f16 (*)[TK])smem;             // [TM][TK], 8 KB
  f16 (*Bs)[TK] = (f16 (*)[TK])(smem + 8192);    // [TN][TK]
  const int m0 = blockIdx.x * TM, n0 = blockIdx.y * TN;
  const int tid = threadIdx.x;
  const int lane = tid & 63, wid = tid >> 6;
  const int wr = wid >> 1, wc = wid & 1;
  const int g = lane >> 4, q16 = lane & 15;

  // staging geometry: chunk = 16 rows = 1024 B; lane l -> row l>>2, 16B slot l&3.
  const int srow = lane >> 2;
  const int skof = (lane & 3) * 8;
  const f16* Ag[2]; char* Al[2];
#pragma unroll
  for (int cb = 0; cb < 2; ++cb) {
    const int ch = wid * 2 + cb;
    Ag[cb] = A + (size_t)(m0 + ch * 16 + srow) * KDIM + skof;
    Al[cb] = (char*)As + ch * 1024;
  }
  const f16* Bg[BCH]; char* Bl[BCH];
#pragma unroll
  for (int cb = 0; cb < BCH; ++cb) {
    const int ch = wid * BCH + cb;
    Bg[cb] = Bt + (size_t)(n0 + ch * 16 + srow) * KDIM + skof;
    Bl[cb] = (char*)Bs + ch * 1024;
  }

  f32x4 zero = {0.f, 0.f, 0.f, 0.f};
  f32x4 acc[4][JN];
#pragma unroll
  for (int i = 0; i < 4; i++)
#pragma unroll
    for (int j = 0; j < JN; j++) acc[i][j] = zero;

  for (int kk = 0; kk < KDIM; kk += TK) {
    g2l16(Ag[0] + kk, Al[0]);
    g2l16(Ag[1] + kk, Al[1]);
#pragma unroll
    for (int cb = 0; cb < BCH; ++cb) g2l16(Bg[cb] + kk, Bl[cb]);
    __syncthreads();   // drains vmcnt (gload_lds) + joins waves
    f16x8 af[4], bfr[JN];
#pragma unroll
    for (int i = 0; i < 4; i++) af[i] = *(const f16x8*)&As[wr * 64 + i * 16 + q16][8 * g];
#pragma unroll
    for (int j = 0; j < JN; j++) bfr[j] = *(const f16x8*)&Bs[wc * (TN / 2) + j * 16 + q16][8 * g];
#pragma unroll
    for (int i = 0; i < 4; i++)
#pragma unroll
      for (int j = 0; j < JN; j++)
        acc[i][j] = __builtin_amdgcn_mfma_f32_16x16x32_f16(af[i], bfr[j], acc[i][j], 0, 0, 0);
    __syncthreads();   // all ds_reads done before next-iter staging overwrites
  }

  if (MODE == 1) {
#pragma unroll
    for (int i = 0; i < 4; i++)
#pragma unroll
      for (int j = 0; j < JN; j++) {
        const int n = n0 + wc * (TN / 2) + j * 16 + q16;
        const float bs = bias[n];
        const int mbase = m0 + wr * 64 + i * 16 + 4 * g;
#pragma unroll
        for (int r = 0; r < 4; r++) Co[(size_t)(mbase + r) * N + n] = acc[i][j][r] + bs;
      }
  } else {
    // ---- LDS-bounce epilogue: acc(+bias,+Q-scale) -> Cs f16 -> coalesced 16B scatter ----
    f16 (*Cs)[136] = (f16 (*)[136])smem;   // aliases As/Bs (dead after final barrier)
#pragma unroll
    for (int i = 0; i < 4; i++)
#pragma unroll
      for (int j = 0; j < JN; j++) {
        const int n = n0 + wc * (TN / 2) + j * 16 + q16;
        const float bs = bias[n];
        const int rr_n = n % 192;                         // section uniform per (i,j)
        const float scale = (rr_n < 64) ? 0.125f : 1.0f;  // Q pre-scaled by 1/8
        const int mrow = wr * 64 + i * 16 + 4 * g;
        const int ncol = wc * (TN / 2) + j * 16 + q16;
#pragma unroll
        for (int r = 0; r < 4; r++)
          Cs[mrow + r][ncol] = (f16)((acc[i][j][r] + bs) * scale);
      }
    __syncthreads();
    const int cc = tid & 15;
    const int nn = n0 + 8 * cc;
    const int hh = nn / 192;
    const int rr = nn - 192 * hh;
    f16* base = (rr < 64) ? Qo : (rr < 128) ? Ko : Vo;
    const int d0 = rr & 63;
#pragma unroll
    for (int it = 0; it < 8; ++it) {
      const int m = (tid >> 4) + 16 * it;
      f16x8 v = *(const f16x8*)&Cs[m][8 * cc];
      const int mglob = m0 + m;
      const int b = mglob >> 12, s = mglob & (S_LEN - 1);
      const size_t bh = (size_t)b * NHEAD + hh;
      *(f16x8*)(base + (bh * S_LEN + s) * HDIM + d0) = v;
    }
  }
}

// ---------------- sliding-window flash attention (LDS window, split-K, 16 waves) ----------------
// Tile-8 chunk B is ALWAYS fully masked (key-query in [129,159] > 128) -> skipped
// entirely (bit-identical: it contributed p==0). Split rebalanced around that:
// kh0 = t0..t3 (t0 masked), kh1 = t4..t8 (t8 chunk-A-masked only) -> critical
// path ~4.5 tile-equivalents instead of 5. Interior blocks skip masks on t1..t7.
#define VSOFF 49152

__global__ __launch_bounds__(1024) void attn_kernel(
    const f16* __restrict__ Q, const f16* __restrict__ K,
    const f16* __restrict__ V, f16* __restrict__ O) {
  __shared__ __align__(16) char smem[98304];

  const int wg = blockIdx.x;
  const int vv = (wg & 7) * 64 + (wg >> 3);    // XCD swizzle (512 % 8 == 0, bijective)
  const int bh = vv >> 5, qc = vv & 31;        // 32 query-chunks of 128 per bh
  const int b = bh >> 3, h = bh & 7;
  const int tid = threadIdx.x;
  const int wid = tid >> 6, lane = tid & 63;
  const int qwv = wid & 7;                     // query-wave id (0..7)
  const int kh = wid >> 3;                     // key half: 0 -> t0..t3, 1 -> t4..t8
  const int g = lane >> 4, q16 = lane & 15;
  const int qb = qc * 128;
  const int wb = qb - 128;
  const int qw = qb + qwv * 16;                // this wave's 16 queries
  const int qg = qw + q16;

  const f16* Kb_g = K + (size_t)bh * S_LEN * HDIM;
  const f16* Vb_g = V + (size_t)bh * S_LEN * HDIM;

#pragma unroll
  for (int rd = 0; rd < 3; ++rd) {
    const int idx = rd * 1024 + tid;
    const int r = idx >> 3, sl = idx & 7;
    const int key = min(max(wb + r, 0), S_LEN - 1); // clamped rows masked in compute
    int4 kvv = *(const int4*)(Kb_g + (size_t)key * HDIM + sl * 8);
    *(int4*)(smem + r * 128 + ((sl ^ (r & 7)) << 4)) = kvv;
  }
#pragma unroll
  for (int rd = 0; rd < 3; ++rd) {
    const int idx = rd * 1024 + tid;
    const int r = idx >> 3, c8 = (idx & 7) * 8;
    const int key = min(max(wb + r, 0), S_LEN - 1);
    int4 vvv = *(const int4*)(Vb_g + (size_t)key * HDIM + c8);
    *(int4*)(smem + VSOFF + (c8 >> 4) * 12288 + (r >> 2) * 128 + (r & 3) * 32 + ((c8 & 8) << 1)) = vvv;
  }
  __syncthreads();

  const f16* Qb = Q + ((size_t)bh * S_LEN + qw) * HDIM;
  f16x8 qf0 = *(const f16x8*)(Qb + q16 * HDIM + 8 * g);
  f16x8 qf1 = *(const f16x8*)(Qb + q16 * HDIM + 32 + 8 * g);

  f32x4 zero = {0.f, 0.f, 0.f, 0.f};
  f32x4 o[4];
#pragma unroll
  for (int dt = 0; dt < 4; dt++) o[dt] = zero;
  float m_run = 0.f;   // static base; vote-guarded rescale
  float l_run = 0.f;

  const unsigned troff = (unsigned)(g * 128 + q16 * 8);

  auto do_tile = [&](int t, bool domask, bool skipB) {
    const int kAp = qwv * 16 + 32 * t;
    const int kBp = kAp + 16;
    const int rrA = kAp + q16;
    const int rrB = kBp + q16;
    f16x8 ka0 = *(const f16x8*)(smem + rrA * 128 + (((g    ) ^ (rrA & 7)) << 4));
    f16x8 ka1 = *(const f16x8*)(smem + rrA * 128 + (((g + 4) ^ (rrA & 7)) << 4));
    f16x8 kb0{}, kb1{};
    if (!skipB) {
      kb0 = *(const f16x8*)(smem + rrB * 128 + (((g    ) ^ (rrB & 7)) << 4));
      kb1 = *(const f16x8*)(smem + rrB * 128 + (((g + 4) ^ (rrB & 7)) << 4));
    }

    f32x4 sA = zero, sB = zero;
    __builtin_amdgcn_s_setprio(1);
    sA = __builtin_amdgcn_mfma_f32_16x16x32_f16(ka0, qf0, sA, 0, 0, 0);
    sA = __builtin_amdgcn_mfma_f32_16x16x32_f16(ka1, qf1, sA, 0, 0, 0);
    if (!skipB) {
      sB = __builtin_amdgcn_mfma_f32_16x16x32_f16(kb0, qf0, sB, 0, 0, 0);
      sB = __builtin_amdgcn_mfma_f32_16x16x32_f16(kb1, qf1, sB, 0, 0, 0);
    }
    __builtin_amdgcn_s_setprio(0);

    float sv[8];
    float mx = -INFINITY;
#pragma unroll
    for (int i = 0; i < 4; i++) {
      if (domask) {
        const int kgA = wb + kAp + 4 * g + i;
        const bool okA = ((unsigned)(kgA - qg + 128) <= 256u) && ((unsigned)kgA < S_LEN);
        sv[i] = okA ? sA[i] : -INFINITY;
      } else {
        sv[i] = sA[i];  // proven in-window + in-sequence
      }
      if (!skipB) {
        if (domask) {
          const int kgB = wb + kBp + 4 * g + i;
          const bool okB = ((unsigned)(kgB - qg + 128) <= 256u) && ((unsigned)kgB < S_LEN);
          sv[i + 4] = okB ? sB[i] : -INFINITY;
        } else {
          sv[i + 4] = sB[i];
        }
      } else {
        sv[i + 4] = -INFINITY;  // chunk B of t=8: always outside window
      }
      mx = fmaxf(mx, fmaxf(sv[i], sv[i + 4]));
    }

    float pA[4], pB[4];
#pragma unroll
    for (int i = 0; i < 4; i++) {
      pA[i] = EXP2F((sv[i] - m_run) * LOG2E);
      if (!skipB) pB[i] = EXP2F((sv[i + 4] - m_run) * LOG2E);
    }

    if (__builtin_expect(!__all(mx - m_run <= 8.f), 0)) {
      float mxq = fmaxf(mx, __shfl_xor(mx, 16));
      mxq = fmaxf(mxq, __shfl_xor(mxq, 32));
      const float mnew = fmaxf(m_run, mxq);
      const float resc = EXP2F((m_run - mnew) * LOG2E);
#pragma unroll
      for (int i = 0; i < 4; i++) { pA[i] *= resc; if (!skipB) pB[i] *= resc; }
      l_run *= resc;
      float ri[4];
#pragma unroll
      for (int i = 0; i < 4; i++) ri[i] = __shfl(resc, 4 * g + i);
#pragma unroll
      for (int dt = 0; dt < 4; dt++)
#pragma unroll
        for (int i = 0; i < 4; i++) o[dt][i] *= ri[i];
      m_run = mnew;
    }

    f16x4 pfA, pfB;
#pragma unroll
    for (int i = 0; i < 4; i++) {
      l_run += pA[i];
      pfA[i] = (f16)pA[i];
      if (!skipB) { l_run += pB[i]; pfB[i] = (f16)pB[i]; }
    }

    const int kcA = kAp;
    const int kcB = kBp;   // only used when !skipB; then kBp <= 368 by schedule
    f16x4 bA[4], bB[4];
#pragma unroll
    for (int dt = 0; dt < 4; ++dt) {
      unsigned aA = (unsigned)(uintptr_t)(smem + VSOFF + dt * 12288 + (kcA >> 2) * 128) + troff;
      asm volatile("ds_read_b64_tr_b16 %0, %1" : "=v"(bA[dt]) : "v"(aA));
      if (!skipB) {
        unsigned aB = (unsigned)(uintptr_t)(smem + VSOFF + dt * 12288 + (kcB >> 2) * 128) + troff;
        asm volatile("ds_read_b64_tr_b16 %0, %1" : "=v"(bB[dt]) : "v"(aB));
      }
    }
    asm volatile("s_waitcnt lgkmcnt(0)" ::: "memory");
    __builtin_amdgcn_sched_barrier(0);

    __builtin_amdgcn_s_setprio(1);
#pragma unroll
    for (int dt = 0; dt < 4; dt++) {
      o[dt] = __builtin_amdgcn_mfma_f32_16x16x16f16(pfA, bA[dt], o[dt], 0, 0, 0);
      if (!skipB)
        o[dt] = __builtin_amdgcn_mfma_f32_16x16x16f16(pfB, bB[dt], o[dt], 0, 0, 0);
    }
    __builtin_amdgcn_s_setprio(0);
  };

  const bool interior = (qb >= 128) && (qb <= S_LEN - 256);  // wb>=0 && wb+384<=S_LEN
  if (interior) {
    if (kh == 0) {
      do_tile(0, true, false);
      do_tile(1, false, false); do_tile(2, false, false); do_tile(3, false, false);
    } else {
      do_tile(4, false, false); do_tile(5, false, false);
      do_tile(6, false, false); do_tile(7, false, false);
      do_tile(8, true, true);   // chunk A partially valid; chunk B provably all-masked
    }
  } else {
    if (kh == 0) {
#pragma unroll
      for (int t = 0; t < 4; ++t) do_tile(t, true, false);
    } else {
#pragma unroll
      for (int t = 4; t < 8; ++t) do_tile(t, true, false);
      do_tile(8, true, true);
    }
  }

  l_run += __shfl_xor(l_run, 16);
  l_run += __shfl_xor(l_run, 32);

  // ---- split-K merge ----
  float* oS = (float*)smem;                    // [8][64][16] f32 = 32 KB
  float* lS = (float*)(smem + 32768);          // [8][64]
  float* mS = (float*)(smem + 34816);          // [8][64]
  __syncthreads();   // all waves done reading K/V LDS
  if (kh == 1) {
#pragma unroll
    for (int dt = 0; dt < 4; dt++)
#pragma unroll
      for (int i = 0; i < 4; i++)
        oS[(qwv * 64 + lane) * 16 + dt * 4 + i] = o[dt][i];
    lS[qwv * 64 + lane] = l_run;
    mS[qwv * 64 + lane] = m_run;
  }
  __syncthreads();   // publish visible
  if (kh == 0) {
    const float mB = mS[qwv * 64 + lane];
    const float lB = lS[qwv * 64 + lane];
    const float m = fmaxf(m_run, mB);
    const float fA = EXP2F((m_run - m) * LOG2E);
    const float fB = EXP2F((mB - m) * LOG2E);
    const float linv = 1.f / (l_run * fA + lB * fB);
    const float aA = fA * linv, aB = fB * linv;   // per query q16
    float aAi[4], aBi[4];
#pragma unroll
    for (int i = 0; i < 4; i++) {
      aAi[i] = __shfl(aA, 4 * g + i);             // per query 4g+i
      aBi[i] = __shfl(aB, 4 * g + i);
    }
    float* st = (float*)(smem + VSOFF) + qwv * 1024;   // 8 x 4 KB
#pragma unroll
    for (int dt = 0; dt < 4; dt++)
#pragma unroll
      for (int i = 0; i < 4; i++) {
        const float ov = o[dt][i] * aAi[i] + oS[(qwv * 64 + lane) * 16 + dt * 4 + i] * aBi[i];
        st[(4 * g + i) * 64 + dt * 16 + q16] = ov;
      }
    const int r = lane >> 2, c0 = (lane & 3) * 16;
    const float* sp = st + r * 64 + c0;
    f16x8 h0, h1;
#pragma unroll
    for (int j = 0; j < 8; j++) { h0[j] = (f16)sp[j]; h1[j] = (f16)sp[8 + j]; }
    f16* dst = O + ((size_t)b * S_LEN + qw + r) * EMB + h * HDIM + c0;
    *(f16x8*)dst = h0;
    *(f16x8*)(dst + 8) = h1;
  }
}

// ---------------- launch ----------------
extern "C" void kernel_launch(void* const* d_in, const int* in_sizes, int n_in,
                              void* d_out, int out_size, void* d_ws, size_t ws_size,
                              hipStream_t stream) {
  const float* x     = (const float*)d_in[0];
  const float* w_qkv = (const float*)d_in[1];
  const float* b_qkv = (const float*)d_in[2];
  const float* w_o   = (const float*)d_in[3];
  const float* b_o   = (const float*)d_in[4];
  float* out = (float*)d_out;

  char* ws = (char*)d_ws;
  f16* xb    = (f16*)(ws);                 // [8192][512]        8.0 MiB
  f16* wqkvt = (f16*)(ws + 8388608);       // [1536][512]        1.5 MiB
  f16* wot   = (f16*)(ws + 9961472);       // [512][512]         0.5 MiB
  f16* Qs    = (f16*)(ws + 10485760);      // [16][4096][64]     8 MiB
  f16* Ks    = (f16*)(ws + 18874368);      // [16][4096][64]     8 MiB
  f16* Vs    = (f16*)(ws + 27262976);      // [16][4096][64]     8 MiB (row-major)
  f16* attn  = (f16*)(ws + 35651584);      // [8192][512]        8 MiB

  prep_kernel<<<2304, 256, 0, stream>>>(x, xb, w_qkv, wqkvt, w_o, wot);
  gemm_bt_kernel<0, 128><<<dim3(64, 12), 256, 0, stream>>>(xb, wqkvt, b_qkv, Qs, Ks, Vs,
                                                           (float*)nullptr, 8192, 1536);
  attn_kernel<<<512, 1024, 0, stream>>>(Qs, Ks, Vs, attn);
  gemm_bt_kernel<1, 64><<<dim3(64, 8), 256, 0, stream>>>(attn, wot, b_o,
                                                         (f16*)nullptr, (f16*)nullptr, (f16*)nullptr,
                                                         out, 8192, 512);
}